// Round 1
// baseline (1219.408 us; speedup 1.0000x reference)
//
#include <hip/hip_runtime.h>

#define NTOK 8192
#define DM 1024
#define DF 4096
#define DH 512
#define NE 4

typedef unsigned short ushort_t;
typedef short bf16x8 __attribute__((ext_vector_type(8)));
typedef float f32x4 __attribute__((ext_vector_type(4)));

__device__ __forceinline__ unsigned short f2bf(float f) {
    unsigned int u = __float_as_uint(f);
    u += 0x7FFFu + ((u >> 16) & 1u);   // round-to-nearest-even
    return (unsigned short)(u >> 16);
}
__device__ __forceinline__ float bf2f(unsigned short h) {
    return __uint_as_float(((unsigned int)h) << 16);
}
__device__ __forceinline__ float gelu_f(float x) {
    return 0.5f * x * (1.0f + erff(x * 0.7071067811865476f));
}
__device__ __forceinline__ void gload16(const void* g, void* l) {
    __builtin_amdgcn_global_load_lds((__attribute__((address_space(1))) void*)(g),
                                     (__attribute__((address_space(3))) void*)(l), 16, 0, 0);
}

// ---------- prep: x -> (xh, xl) bf16 split, row-major ----------
__global__ __launch_bounds__(256) void k_cast_split(const float* __restrict__ in,
                                                    ushort_t* __restrict__ hi,
                                                    ushort_t* __restrict__ lo, int n4) {
    int i = blockIdx.x * 256 + threadIdx.x;
    if (i >= n4) return;
    float4 v = ((const float4*)in)[i];
    ushort4 h, l;
    h.x = f2bf(v.x); l.x = f2bf(v.x - bf2f(h.x));
    h.y = f2bf(v.y); l.y = f2bf(v.y - bf2f(h.y));
    h.z = f2bf(v.z); l.z = f2bf(v.z - bf2f(h.z));
    h.w = f2bf(v.w); l.w = f2bf(v.w - bf2f(h.w));
    ((ushort4*)hi)[i] = h;
    ((ushort4*)lo)[i] = l;
}

// ---------- prep: [E][K][N] fp32 -> [E][N][K] bf16 (optionally split) ----------
template <bool SPLIT>
__global__ __launch_bounds__(256) void k_tcast(const float* __restrict__ in,
                                               ushort_t* __restrict__ oh,
                                               ushort_t* __restrict__ ol, int K, int N) {
    __shared__ float t[64][65];
    size_t base = (size_t)blockIdx.z * K * N;
    const float* src = in + base;
    int k0 = blockIdx.y * 64, n0 = blockIdx.x * 64;
    int tx = threadIdx.x & 63, ty = threadIdx.x >> 6;
#pragma unroll
    for (int i = 0; i < 16; i++) {
        int r = ty + i * 4;
        t[r][tx] = src[(size_t)(k0 + r) * N + n0 + tx];
    }
    __syncthreads();
#pragma unroll
    for (int i = 0; i < 16; i++) {
        int nn = ty + i * 4;
        float v = t[tx][nn];
        unsigned short hv = f2bf(v);
        size_t o = base + (size_t)(n0 + nn) * K + k0 + tx;
        oh[o] = hv;
        if (SPLIT) ol[o] = f2bf(v - bf2f(hv));
    }
}

// ---------- MFMA GEMM: C[M,N] = sum_p A_p[M,K] * B_p[N,K]^T  (m97 structure) ----------
// EPI 0: h = gelu(acc + br1[col])            -> outF (fp32, stride N)
// EPI 1: ghid = gate[row,e]*gelu(acc+b1[col])-> outB (bf16, stride N)
// EPI 2: out = acc + gate[row,e]*b2[col]     -> outF (fp32, write)
// EPI 3: out += acc + gate[row,e]*b2[col]    -> outF (fp32, rmw)
template <int EPI, int NPASS>
__global__ __launch_bounds__(256) void k_gemm(const ushort_t* __restrict__ A0, const ushort_t* __restrict__ B0,
                                              const ushort_t* __restrict__ A1, const ushort_t* __restrict__ B1,
                                              const ushort_t* __restrict__ A2, const ushort_t* __restrict__ B2,
                                              int K, int N,
                                              const float* __restrict__ bias,
                                              const float* __restrict__ gate, int expert,
                                              float* __restrict__ outF, ushort_t* __restrict__ outB) {
    __shared__ ushort_t lA[4096];   // 128 rows x 32 k, linear (global_load_lds dest)
    __shared__ ushort_t lB[4096];
    int row0 = blockIdx.y * 128, col0 = blockIdx.x * 128;
    int tid = threadIdx.x, lane = tid & 63, wv = tid >> 6;
    int wr = wv >> 1, wc = wv & 1;
    int r15 = lane & 15, hq = lane >> 4;

    f32x4 z = {0.f, 0.f, 0.f, 0.f};
    f32x4 acc[4][4];
#pragma unroll
    for (int m = 0; m < 4; m++)
#pragma unroll
        for (int n = 0; n < 4; n++) acc[m][n] = z;

    // staging chunk decomposition: chunk c in [0,512): row=c>>2, kchunk=c&3 (8 elems each)
    int c0 = tid, c1 = tid + 256;
    int rA0 = c0 >> 2, kc0 = c0 & 3;
    int rA1 = c1 >> 2, kc1 = c1 & 3;
    char* ldA0 = (char*)lA + wv * 1024;          // wave-uniform LDS dests
    char* ldA1 = (char*)lA + 4096 + wv * 1024;
    char* ldB0 = (char*)lB + wv * 1024;
    char* ldB1 = (char*)lB + 4096 + wv * 1024;

#pragma unroll
    for (int p = 0; p < NPASS; p++) {
        const ushort_t* A = (p == 0) ? A0 : ((p == 1) ? A1 : A2);
        const ushort_t* B = (p == 0) ? B0 : ((p == 1) ? B1 : B2);
        const ushort_t* Ab0 = A + (size_t)(row0 + rA0) * K + kc0 * 8;
        const ushort_t* Ab1 = A + (size_t)(row0 + rA1) * K + kc1 * 8;
        const ushort_t* Bb0 = B + (size_t)(col0 + rA0) * K + kc0 * 8;
        const ushort_t* Bb1 = B + (size_t)(col0 + rA1) * K + kc1 * 8;
        for (int kt = 0; kt < K; kt += 32) {
            gload16(Ab0 + kt, ldA0);
            gload16(Ab1 + kt, ldA1);
            gload16(Bb0 + kt, ldB0);
            gload16(Bb1 + kt, ldB1);
            __syncthreads();
            bf16x8 af[4], bfr[4];
#pragma unroll
            for (int m = 0; m < 4; m++)
                af[m] = *(const bf16x8*)(lA + (wr * 64 + m * 16 + r15) * 32 + hq * 8);
#pragma unroll
            for (int n = 0; n < 4; n++)
                bfr[n] = *(const bf16x8*)(lB + (wc * 64 + n * 16 + r15) * 32 + hq * 8);
#pragma unroll
            for (int m = 0; m < 4; m++)
#pragma unroll
                for (int n = 0; n < 4; n++)
                    acc[m][n] = __builtin_amdgcn_mfma_f32_16x16x32_bf16(af[m], bfr[n], acc[m][n], 0, 0, 0);
            __syncthreads();
        }
    }

    // epilogue; C layout: col = lane&15, row = (lane>>4)*4 + q  [m89-verified]
#pragma unroll
    for (int m = 0; m < 4; m++) {
#pragma unroll
        for (int n = 0; n < 4; n++) {
#pragma unroll
            for (int q = 0; q < 4; q++) {
                int row = row0 + wr * 64 + m * 16 + hq * 4 + q;
                int col = col0 + wc * 64 + n * 16 + r15;
                float v = acc[m][n][q];
                if (EPI == 0) {
                    v = gelu_f(v + bias[col]);
                    outF[(size_t)row * N + col] = v;
                } else if (EPI == 1) {
                    v = gelu_f(v + bias[col]) * gate[row * 4 + expert];
                    outB[(size_t)row * N + col] = f2bf(v);
                } else {
                    float g = gate[row * 4 + expert];
                    v += g * bias[col];
                    if (EPI == 3) v += outF[(size_t)row * N + col];
                    outF[(size_t)row * N + col] = v;
                }
            }
        }
    }
}

// ---------- router: logits (fp32), top-2 threshold, masked softmax ----------
__global__ __launch_bounds__(256) void k_gate(const float* __restrict__ h,
                                              const float* __restrict__ wr2,
                                              const float* __restrict__ br2,
                                              float* __restrict__ gate) {
    int t = blockIdx.x * 4 + (threadIdx.x >> 6);
    int lane = threadIdx.x & 63;
    const float* hr = h + (size_t)t * DH;
    const float4* w4 = (const float4*)wr2;
    float gx = 0.f, gy = 0.f, gz = 0.f, gw = 0.f;
#pragma unroll
    for (int j = 0; j < 8; j++) {
        int k = lane * 8 + j;
        float hv = hr[k];
        float4 w = w4[k];
        gx += hv * w.x; gy += hv * w.y; gz += hv * w.z; gw += hv * w.w;
    }
#pragma unroll
    for (int off = 32; off > 0; off >>= 1) {
        gx += __shfl_xor(gx, off);
        gy += __shfl_xor(gy, off);
        gz += __shfl_xor(gz, off);
        gw += __shfl_xor(gw, off);
    }
    if (lane == 0) {
        float ls[4];
        ls[0] = gx + br2[0]; ls[1] = gy + br2[1]; ls[2] = gz + br2[2]; ls[3] = gw + br2[3];
        float m1 = -1e30f, m2 = -1e30f;
#pragma unroll
        for (int i = 0; i < 4; i++) {
            float v = ls[i];
            if (v > m1) { m2 = m1; m1 = v; }
            else if (v > m2) { m2 = v; }
        }
        float e0 = (ls[0] >= m2) ? expf(ls[0] - m1) : 0.f;
        float e1 = (ls[1] >= m2) ? expf(ls[1] - m1) : 0.f;
        float e2 = (ls[2] >= m2) ? expf(ls[2] - m1) : 0.f;
        float e3 = (ls[3] >= m2) ? expf(ls[3] - m1) : 0.f;
        float iz = 1.f / (e0 + e1 + e2 + e3);
        float4 g = {e0 * iz, e1 * iz, e2 * iz, e3 * iz};
        ((float4*)gate)[t] = g;
    }
}

extern "C" void kernel_launch(void* const* d_in, const int* in_sizes, int n_in,
                              void* d_out, int out_size, void* d_ws, size_t ws_size,
                              hipStream_t stream) {
    const float* x   = (const float*)d_in[0];
    const float* w1  = (const float*)d_in[1];
    const float* b1  = (const float*)d_in[2];
    const float* w2  = (const float*)d_in[3];
    const float* b2  = (const float*)d_in[4];
    const float* wr1 = (const float*)d_in[5];
    const float* br1 = (const float*)d_in[6];
    const float* wr2 = (const float*)d_in[7];
    const float* br2 = (const float*)d_in[8];
    float* out  = (float*)d_out;
    float* gate = out + (size_t)NTOK * DM;   // outputs concat: [out | gate]

    // workspace layout (≈178 MB)
    ushort_t* xh    = (ushort_t*)d_ws;                     // [8192][1024]
    ushort_t* xl    = xh + (size_t)NTOK * DM;
    ushort_t* w1T   = xl + (size_t)NTOK * DM;              // [4][4096][1024]  (N-major)
    ushort_t* w2T   = w1T + (size_t)NE * DM * DF;          // [4][1024][4096]  (N-major)
    ushort_t* wr1Th = w2T + (size_t)NE * DF * DM;          // [512][1024]
    ushort_t* wr1Tl = wr1Th + (size_t)DM * DH;
    float*    h     = (float*)(wr1Tl + (size_t)DM * DH);   // [8192][512] fp32
    ushort_t* ghid  = (ushort_t*)(h + (size_t)NTOK * DH);  // [8192][4096] bf16 (per expert, reused)

    // prep
    k_cast_split<<<NTOK * DM / 4 / 256, 256, 0, stream>>>(x, xh, xl, NTOK * DM / 4);
    k_tcast<false><<<dim3(DF / 64, DM / 64, NE), 256, 0, stream>>>(w1, w1T, nullptr, DM, DF);
    k_tcast<false><<<dim3(DM / 64, DF / 64, NE), 256, 0, stream>>>(w2, w2T, nullptr, DF, DM);
    k_tcast<true ><<<dim3(DH / 64, DM / 64, 1),  256, 0, stream>>>(wr1, wr1Th, wr1Tl, DM, DH);

    // router: h = gelu(x@wr1 + br1), 3-term bf16-split for fp32-grade logits
    k_gemm<0, 3><<<dim3(DH / 128, NTOK / 128), 256, 0, stream>>>(
        xh, wr1Th, xh, wr1Tl, xl, wr1Th, DM, DH, br1, nullptr, 0, h, nullptr);
    k_gate<<<NTOK / 4, 256, 0, stream>>>(h, wr2, br2, gate);

    // experts (dense this round; top-2 sparsity is the next optimization)
    for (int e = 0; e < NE; e++) {
        k_gemm<1, 1><<<dim3(DF / 128, NTOK / 128), 256, 0, stream>>>(
            xh, w1T + (size_t)e * DM * DF, nullptr, nullptr, nullptr, nullptr,
            DM, DF, b1 + e * DF, gate, e, nullptr, ghid);
        if (e == 0)
            k_gemm<2, 1><<<dim3(DM / 128, NTOK / 128), 256, 0, stream>>>(
                ghid, w2T + (size_t)e * DF * DM, nullptr, nullptr, nullptr, nullptr,
                DF, DM, b2 + e * DM, gate, e, out, nullptr);
        else
            k_gemm<3, 1><<<dim3(DM / 128, NTOK / 128), 256, 0, stream>>>(
                ghid, w2T + (size_t)e * DF * DM, nullptr, nullptr, nullptr, nullptr,
                DF, DM, b2 + e * DM, gate, e, out, nullptr);
    }
}

// Round 3
// 967.785 us; speedup vs baseline: 1.2600x; 1.2600x over previous
//
#include <hip/hip_runtime.h>

#define NTOK 8192
#define DM 1024
#define DF 4096
#define DH 512
#define NE 4
#define SLOTS (NTOK * 2)

typedef unsigned short ushort_t;
typedef short bf16x8 __attribute__((ext_vector_type(8)));
typedef float f32x4 __attribute__((ext_vector_type(4)));

__device__ __forceinline__ unsigned short f2bf(float f) {
    unsigned int u = __float_as_uint(f);
    u += 0x7FFFu + ((u >> 16) & 1u);   // RNE
    return (unsigned short)(u >> 16);
}
__device__ __forceinline__ float bf2f(unsigned short h) {
    return __uint_as_float(((unsigned int)h) << 16);
}
__device__ __forceinline__ float gelu_exact(float x) {
    return 0.5f * x * (1.0f + erff(x * 0.7071067811865476f));
}
__device__ __forceinline__ float gelu_fast(float x) {
    // x * sigmoid(2*sqrt(2/pi)*(x + 0.044715 x^3)); |err| <~1e-3
    float u = 1.5957691216057308f * (x + 0.044715f * x * x * x);
    return x / (1.0f + __expf(-u));
}
__device__ __forceinline__ void gload16(const void* g, void* l) {
    __builtin_amdgcn_global_load_lds((__attribute__((address_space(1))) void*)(g),
                                     (__attribute__((address_space(3))) void*)(l), 16, 0, 0);
}
// LDS bank swizzle: XOR byte bits 4-5 with row bits 1-2 (byte bits 7-8). Involution.
__device__ __forceinline__ int swz(int b) { return b ^ (((b >> 7) & 3) << 4); }
__device__ __forceinline__ int imin(int a, int b) { return a < b ? a : b; }

// ---------- prep: x -> (xh, xl) bf16 split ----------
__global__ __launch_bounds__(256) void k_cast_split(const float* __restrict__ in,
                                                    ushort_t* __restrict__ hi,
                                                    ushort_t* __restrict__ lo, int n4) {
    int i = blockIdx.x * 256 + threadIdx.x;
    if (i >= n4) return;
    float4 v = ((const float4*)in)[i];
    ushort4 h, l;
    h.x = f2bf(v.x); l.x = f2bf(v.x - bf2f(h.x));
    h.y = f2bf(v.y); l.y = f2bf(v.y - bf2f(h.y));
    h.z = f2bf(v.z); l.z = f2bf(v.z - bf2f(h.z));
    h.w = f2bf(v.w); l.w = f2bf(v.w - bf2f(h.w));
    ((ushort4*)hi)[i] = h;
    ((ushort4*)lo)[i] = l;
}

// ---------- prep: [E][K][N] fp32 -> [E][N][K] bf16 (optional split) ----------
template <bool SPLIT>
__global__ __launch_bounds__(256) void k_tcast(const float* __restrict__ in,
                                               ushort_t* __restrict__ oh,
                                               ushort_t* __restrict__ ol, int K, int N) {
    __shared__ float t[64][65];
    size_t base = (size_t)blockIdx.z * K * N;
    const float* src = in + base;
    int k0 = blockIdx.y * 64, n0 = blockIdx.x * 64;
    int tx = threadIdx.x & 63, ty = threadIdx.x >> 6;
#pragma unroll
    for (int i = 0; i < 16; i++) {
        int r = ty + i * 4;
        t[r][tx] = src[(size_t)(k0 + r) * N + n0 + tx];
    }
    __syncthreads();
#pragma unroll
    for (int i = 0; i < 16; i++) {
        int nn = ty + i * 4;
        float v = t[tx][nn];
        unsigned short hv = f2bf(v);
        size_t o = base + (size_t)(n0 + nn) * K + k0 + tx;
        oh[o] = hv;
        if (SPLIT) ol[o] = f2bf(v - bf2f(hv));
    }
}

// ---------- MFMA GEMM, 128x128 tile, BK=32, m97 structure + bank swizzle ----------
// MODE 0: dense router, 3 passes (xh*wh + xh*wl + xl*wh), EPI: h=gelu_exact(acc+br1) fp32
// MODE 1: tiled gather over expert token lists, EPI: ghid = gate*gelu_fast(acc+b1) bf16
// MODE 2: tiled over ghid slots,               EPI: atomicAdd(out[token][col], acc)
template <int MODE>
__global__ __launch_bounds__(256) void k_gemm(
    const ushort_t* __restrict__ A0, const ushort_t* __restrict__ B0,
    const ushort_t* __restrict__ A1, const ushort_t* __restrict__ B1,
    const ushort_t* __restrict__ A2, const ushort_t* __restrict__ B2,
    int K, int N,
    const float* __restrict__ bias, const float* __restrict__ gate,
    const int* __restrict__ idx, const int4* __restrict__ tiles,
    const int* __restrict__ meta,
    float* __restrict__ outF, ushort_t* __restrict__ ghid, float* __restrict__ outA)
{
    int e = 0, rstart = 0, rows = 128, gbase = 0;
    if (MODE != 0) {
        if ((int)blockIdx.y >= meta[0]) return;   // block-uniform: no divergent barrier
        int4 ti = tiles[blockIdx.y];
        e = ti.x; rstart = ti.y; rows = ti.z; gbase = ti.w;
    }
    __shared__ ushort_t lA[4096];   // 8KB: [128 rows][32 k] bf16, bank-swizzled
    __shared__ ushort_t lB[4096];
    int row0 = (MODE == 0) ? blockIdx.y * 128 : 0;
    int col0 = blockIdx.x * 128;
    int tid = threadIdx.x, lane = tid & 63, wv = tid >> 6;
    int wr = wv >> 1, wc = wv & 1;
    int r15 = lane & 15, hq = lane >> 4;

    f32x4 z = {0.f, 0.f, 0.f, 0.f};
    f32x4 acc[4][4];
#pragma unroll
    for (int m = 0; m < 4; m++)
#pragma unroll
        for (int n = 0; n < 4; n++) acc[m][n] = z;

    // staging: thread tid fills LDS bytes d0=tid*16 (rows 0-63) and d1=d0+4096 (rows 64-127).
    // source chunk = inverse-swizzle of destination (rule #21: linear dest, pre-swizzled src).
    int d0 = tid * 16, d1 = d0 + 4096;
    int u0 = swz(d0), u1 = swz(d1);
    int rA0 = u0 >> 6, ko0 = ((u0 >> 4) & 3) * 8;
    int rA1 = u1 >> 6, ko1 = ((u1 >> 4) & 3) * 8;
    char* ldA0 = (char*)lA + wv * 1024;
    char* ldA1 = (char*)lA + 4096 + wv * 1024;
    char* ldB0 = (char*)lB + wv * 1024;
    char* ldB1 = (char*)lB + 4096 + wv * 1024;

    auto compute = [&]() {
        bf16x8 af[4], bfr[4];
#pragma unroll
        for (int m = 0; m < 4; m++) {
            int u = ((wr * 64 + m * 16 + r15) << 6) + (hq << 4);
            af[m] = *(const bf16x8*)((const char*)lA + swz(u));
        }
#pragma unroll
        for (int n = 0; n < 4; n++) {
            int u = ((wc * 64 + n * 16 + r15) << 6) + (hq << 4);
            bfr[n] = *(const bf16x8*)((const char*)lB + swz(u));
        }
#pragma unroll
        for (int m = 0; m < 4; m++)
#pragma unroll
            for (int n = 0; n < 4; n++)
                acc[m][n] = __builtin_amdgcn_mfma_f32_16x16x32_bf16(af[m], bfr[n], acc[m][n], 0, 0, 0);
    };

    if (MODE == 0) {
#pragma unroll
        for (int p = 0; p < 3; p++) {
            const ushort_t* A = (p == 0) ? A0 : ((p == 1) ? A1 : A2);
            const ushort_t* B = (p == 0) ? B0 : ((p == 1) ? B1 : B2);
            const ushort_t* Ab0 = A + (size_t)(row0 + rA0) * K + ko0;
            const ushort_t* Ab1 = A + (size_t)(row0 + rA1) * K + ko1;
            const ushort_t* Bb0 = B + (size_t)(col0 + rA0) * K + ko0;
            const ushort_t* Bb1 = B + (size_t)(col0 + rA1) * K + ko1;
            for (int kt = 0; kt < K; kt += 32) {
                gload16(Ab0 + kt, ldA0);
                gload16(Ab1 + kt, ldA1);
                gload16(Bb0 + kt, ldB0);
                gload16(Bb1 + kt, ldB1);
                __syncthreads();
                compute();
                __syncthreads();
            }
        }
    } else {
        const ushort_t *Ab0, *Ab1, *Bb0, *Bb1;
        if (MODE == 1) {
            int t0 = idx[e * NTOK + rstart + imin(rA0, rows - 1)];
            int t1 = idx[e * NTOK + rstart + imin(rA1, rows - 1)];
            Ab0 = A0 + (size_t)t0 * K + ko0;
            Ab1 = A0 + (size_t)t1 * K + ko1;
            Bb0 = B0 + ((size_t)e * DF + col0 + rA0) * K + ko0;
            Bb1 = B0 + ((size_t)e * DF + col0 + rA1) * K + ko1;
        } else {
            Ab0 = A0 + (size_t)(gbase + imin(rA0, rows - 1)) * K + ko0;
            Ab1 = A0 + (size_t)(gbase + imin(rA1, rows - 1)) * K + ko1;
            Bb0 = B0 + ((size_t)e * DM + col0 + rA0) * K + ko0;
            Bb1 = B0 + ((size_t)e * DM + col0 + rA1) * K + ko1;
        }
        for (int kt = 0; kt < K; kt += 32) {
            gload16(Ab0 + kt, ldA0);
            gload16(Ab1 + kt, ldA1);
            gload16(Bb0 + kt, ldB0);
            gload16(Bb1 + kt, ldB1);
            __syncthreads();
            compute();
            __syncthreads();
        }
    }

    // epilogue; C layout: col = lane&15, row = (lane>>4)*4 + q  [m89-verified]
    if (MODE == 0) {
#pragma unroll
        for (int m = 0; m < 4; m++)
#pragma unroll
            for (int q = 0; q < 4; q++) {
                int row = row0 + wr * 64 + m * 16 + hq * 4 + q;
#pragma unroll
                for (int n = 0; n < 4; n++) {
                    int col = col0 + wc * 64 + n * 16 + r15;
                    outF[(size_t)row * N + col] = gelu_exact(acc[m][n][q] + bias[col]);
                }
            }
    } else if (MODE == 1) {
#pragma unroll
        for (int m = 0; m < 4; m++)
#pragma unroll
            for (int q = 0; q < 4; q++) {
                int lr = wr * 64 + m * 16 + hq * 4 + q;
                if (lr < rows) {
                    int token = idx[e * NTOK + rstart + lr];
                    float g = gate[token * 4 + e];
                    size_t rb = (size_t)(gbase + lr) * N;
#pragma unroll
                    for (int n = 0; n < 4; n++) {
                        int col = col0 + wc * 64 + n * 16 + r15;
                        float v = gelu_fast(acc[m][n][q] + bias[(size_t)e * N + col]) * g;
                        ghid[rb + col] = f2bf(v);
                    }
                }
            }
    } else {
#pragma unroll
        for (int m = 0; m < 4; m++)
#pragma unroll
            for (int q = 0; q < 4; q++) {
                int lr = wr * 64 + m * 16 + hq * 4 + q;
                if (lr < rows) {
                    int token = idx[e * NTOK + rstart + lr];
#pragma unroll
                    for (int n = 0; n < 4; n++) {
                        int col = col0 + wc * 64 + n * 16 + r15;
                        atomicAdd(&outA[(size_t)token * N + col], acc[m][n][q]);
                    }
                }
            }
    }
}

// ---------- router gate: fp32 logits, top-2, softmax, expert token lists ----------
__global__ __launch_bounds__(256) void k_gate(const float* __restrict__ h,
                                              const float* __restrict__ wr2,
                                              const float* __restrict__ br2,
                                              float* __restrict__ gate,
                                              int* __restrict__ cnt,
                                              int* __restrict__ idx) {
    int t = blockIdx.x * 4 + (threadIdx.x >> 6);
    int lane = threadIdx.x & 63;
    const float* hr = h + (size_t)t * DH;
    const float4* w4 = (const float4*)wr2;
    float gx = 0.f, gy = 0.f, gz = 0.f, gw = 0.f;
#pragma unroll
    for (int j = 0; j < 8; j++) {
        int k = lane * 8 + j;
        float hv = hr[k];
        float4 w = w4[k];
        gx += hv * w.x; gy += hv * w.y; gz += hv * w.z; gw += hv * w.w;
    }
#pragma unroll
    for (int off = 32; off > 0; off >>= 1) {
        gx += __shfl_xor(gx, off);
        gy += __shfl_xor(gy, off);
        gz += __shfl_xor(gz, off);
        gw += __shfl_xor(gw, off);
    }
    if (lane == 0) {
        float ls[4];
        ls[0] = gx + br2[0]; ls[1] = gy + br2[1]; ls[2] = gz + br2[2]; ls[3] = gw + br2[3];
        int i1 = 0; float m1 = ls[0];
#pragma unroll
        for (int i = 1; i < 4; i++) if (ls[i] > m1) { m1 = ls[i]; i1 = i; }
        int i2 = -1; float m2 = -1e30f;
#pragma unroll
        for (int i = 0; i < 4; i++) if (i != i1 && ls[i] > m2) { m2 = ls[i]; i2 = i; }
        float e0 = (ls[0] >= m2) ? expf(ls[0] - m1) : 0.f;
        float e1 = (ls[1] >= m2) ? expf(ls[1] - m1) : 0.f;
        float e2 = (ls[2] >= m2) ? expf(ls[2] - m1) : 0.f;
        float e3 = (ls[3] >= m2) ? expf(ls[3] - m1) : 0.f;
        float iz = 1.f / (e0 + e1 + e2 + e3);
        float4 g = {e0 * iz, e1 * iz, e2 * iz, e3 * iz};
        ((float4*)gate)[t] = g;
        int s0 = atomicAdd(&cnt[i1], 1);
        idx[i1 * NTOK + s0] = t;
        int s1 = atomicAdd(&cnt[i2], 1);
        idx[i2 * NTOK + s1] = t;
    }
}

// ---------- tile table over per-expert lists ----------
__global__ void k_tiles(const int* __restrict__ cnt, int4* __restrict__ tiles,
                        int* __restrict__ meta) {
    if (threadIdx.x != 0 || blockIdx.x != 0) return;
    int base = 0, nt = 0;
    for (int e = 0; e < NE; e++) {
        int c = cnt[e];
        for (int r = 0; r < c; r += 128) {
            int4 ti;
            ti.x = e; ti.y = r; ti.z = (c - r < 128) ? (c - r) : 128; ti.w = base + r;
            tiles[nt++] = ti;
        }
        base += c;
    }
    meta[0] = nt;
}

// ---------- out init: out[t][d] = sum_e gate[t][e] * b2[e][d] ----------
__global__ __launch_bounds__(256) void k_init_out(const float* __restrict__ gate,
                                                  const float* __restrict__ b2,
                                                  float* __restrict__ out) {
    int i = blockIdx.x * 256 + threadIdx.x;    // over NTOK*DM/4
    int t = i >> 8;
    int c4 = i & 255;
    float4 g = ((const float4*)gate)[t];
    const float4* b = (const float4*)b2;
    float4 v0 = b[c4], v1 = b[256 + c4], v2 = b[512 + c4], v3 = b[768 + c4];
    float4 o;
    o.x = g.x * v0.x + g.y * v1.x + g.z * v2.x + g.w * v3.x;
    o.y = g.x * v0.y + g.y * v1.y + g.z * v2.y + g.w * v3.y;
    o.z = g.x * v0.z + g.y * v1.z + g.z * v2.z + g.w * v3.z;
    o.w = g.x * v0.w + g.y * v1.w + g.z * v2.w + g.w * v3.w;
    ((float4*)out)[i] = o;
}

extern "C" void kernel_launch(void* const* d_in, const int* in_sizes, int n_in,
                              void* d_out, int out_size, void* d_ws, size_t ws_size,
                              hipStream_t stream) {
    const float* x   = (const float*)d_in[0];
    const float* w1  = (const float*)d_in[1];
    const float* b1  = (const float*)d_in[2];
    const float* w2  = (const float*)d_in[3];
    const float* b2  = (const float*)d_in[4];
    const float* wr1 = (const float*)d_in[5];
    const float* br1 = (const float*)d_in[6];
    const float* wr2 = (const float*)d_in[7];
    const float* br2 = (const float*)d_in[8];
    float* out  = (float*)d_out;
    float* gate = out + (size_t)NTOK * DM;

    // workspace (~216 MB): ghid region overlays xl+h (both dead before GEMM1)
    char* p = (char*)d_ws;
    auto take = [&](size_t bytes) { char* r = p; p += (bytes + 255) & ~(size_t)255; return r; };
    ushort_t* xh    = (ushort_t*)take((size_t)NTOK * DM * 2);
    ushort_t* w1T   = (ushort_t*)take((size_t)NE * DF * DM * 2);   // [e][N=DF][K=DM]
    ushort_t* w2T   = (ushort_t*)take((size_t)NE * DM * DF * 2);   // [e][N=DM][K=DF]
    ushort_t* wr1Th = (ushort_t*)take((size_t)DH * DM * 2);        // [N=DH][K=DM]
    ushort_t* wr1Tl = (ushort_t*)take((size_t)DH * DM * 2);
    int*      cnt   = (int*)take(64);
    int*      idx   = (int*)take((size_t)NE * NTOK * 4);
    int4*     tiles = (int4*)take(144 * 16);
    int*      meta  = (int*)take(64);
    char*     region = take((size_t)SLOTS * DF * 2);               // 134 MB
    ushort_t* xl    = (ushort_t*)region;
    float*    h     = (float*)(region + (size_t)NTOK * DM * 2);
    ushort_t* ghid  = (ushort_t*)region;                           // [slot][DF]

    hipMemsetAsync(cnt, 0, 64, stream);

    // prep
    k_cast_split<<<NTOK * DM / 4 / 256, 256, 0, stream>>>(x, xh, xl, NTOK * DM / 4);
    k_tcast<false><<<dim3(DF / 64, DM / 64, NE), 256, 0, stream>>>(w1, w1T, nullptr, DM, DF);
    k_tcast<false><<<dim3(DM / 64, DF / 64, NE), 256, 0, stream>>>(w2, w2T, nullptr, DF, DM);
    k_tcast<true ><<<dim3(DH / 64, DM / 64, 1),  256, 0, stream>>>(wr1, wr1Th, wr1Tl, DM, DH);

    // router: h = gelu(x@wr1 + br1), fp32-grade via bf16 3-term split
    k_gemm<0><<<dim3(DH / 128, NTOK / 128), 256, 0, stream>>>(
        xh, wr1Th, xh, wr1Tl, xl, wr1Th, DM, DH, br1,
        nullptr, nullptr, nullptr, nullptr, h, nullptr, nullptr);
    k_gate<<<NTOK / 4, 256, 0, stream>>>(h, wr2, br2, gate, cnt, idx);
    k_tiles<<<1, 64, 0, stream>>>(cnt, tiles, meta);
    k_init_out<<<NTOK * DM / 4 / 256, 256, 0, stream>>>(gate, b2, out);

    // sparse expert GEMMs (top-2: 16384 slot-rows total, <=132 tiles)
    k_gemm<1><<<dim3(DF / 128, 132), 256, 0, stream>>>(
        xh, w1T, nullptr, nullptr, nullptr, nullptr, DM, DF, b1,
        gate, idx, tiles, meta, nullptr, ghid, nullptr);
    k_gemm<2><<<dim3(DM / 128, 132), 256, 0, stream>>>(
        ghid, w2T, nullptr, nullptr, nullptr, nullptr, DF, DM, nullptr,
        nullptr, idx, tiles, meta, nullptr, nullptr, out);
}

// Round 4
// 948.967 us; speedup vs baseline: 1.2850x; 1.0198x over previous
//
#include <hip/hip_runtime.h>

#define NTOK 8192
#define DM 1024
#define DF 4096
#define DH 512
#define NE 4
#define SLOTS (NTOK * 2)
#define NYT_MAX 132

typedef unsigned short ushort_t;
typedef short bf16x8 __attribute__((ext_vector_type(8)));
typedef float f32x4 __attribute__((ext_vector_type(4)));

__device__ __forceinline__ unsigned short f2bf(float f) {
    unsigned int u = __float_as_uint(f);
    u += 0x7FFFu + ((u >> 16) & 1u);   // RNE
    return (unsigned short)(u >> 16);
}
__device__ __forceinline__ float bf2f(unsigned short h) {
    return __uint_as_float(((unsigned int)h) << 16);
}
__device__ __forceinline__ float gelu_exact(float x) {
    return 0.5f * x * (1.0f + erff(x * 0.7071067811865476f));
}
__device__ __forceinline__ float gelu_fast(float x) {
    float u = 1.5957691216057308f * (x + 0.044715f * x * x * x);
    return x / (1.0f + __expf(-u));
}
__device__ __forceinline__ void gload16(const void* g, void* l) {
    __builtin_amdgcn_global_load_lds((__attribute__((address_space(1))) void*)(g),
                                     (__attribute__((address_space(3))) void*)(l), 16, 0, 0);
}
// LDS bank swizzle: XOR byte bits 4-5 with row bits 1-2 (byte bits 7-8). Involution.
// Verified round 3: SQ_LDS_BANK_CONFLICT == 0.
__device__ __forceinline__ int swz(int b) { return b ^ (((b >> 7) & 3) << 4); }
__device__ __forceinline__ int imin(int a, int b) { return a < b ? a : b; }

// ---------- prep: x -> (xh, xl) bf16 split ----------
__global__ __launch_bounds__(256) void k_cast_split(const float* __restrict__ in,
                                                    ushort_t* __restrict__ hi,
                                                    ushort_t* __restrict__ lo, int n4) {
    int i = blockIdx.x * 256 + threadIdx.x;
    if (i >= n4) return;
    float4 v = ((const float4*)in)[i];
    ushort4 h, l;
    h.x = f2bf(v.x); l.x = f2bf(v.x - bf2f(h.x));
    h.y = f2bf(v.y); l.y = f2bf(v.y - bf2f(h.y));
    h.z = f2bf(v.z); l.z = f2bf(v.z - bf2f(h.z));
    h.w = f2bf(v.w); l.w = f2bf(v.w - bf2f(h.w));
    ((ushort4*)hi)[i] = h;
    ((ushort4*)lo)[i] = l;
}

// ---------- prep: [E][K][N] fp32 -> [E][N][K] bf16 (optional split) ----------
template <bool SPLIT>
__global__ __launch_bounds__(256) void k_tcast(const float* __restrict__ in,
                                               ushort_t* __restrict__ oh,
                                               ushort_t* __restrict__ ol, int K, int N) {
    __shared__ float t[64][65];
    size_t base = (size_t)blockIdx.z * K * N;
    const float* src = in + base;
    int k0 = blockIdx.y * 64, n0 = blockIdx.x * 64;
    int tx = threadIdx.x & 63, ty = threadIdx.x >> 6;
#pragma unroll
    for (int i = 0; i < 16; i++) {
        int r = ty + i * 4;
        t[r][tx] = src[(size_t)(k0 + r) * N + n0 + tx];
    }
    __syncthreads();
#pragma unroll
    for (int i = 0; i < 16; i++) {
        int nn = ty + i * 4;
        float v = t[tx][nn];
        unsigned short hv = f2bf(v);
        size_t o = base + (size_t)(n0 + nn) * K + k0 + tx;
        oh[o] = hv;
        if (SPLIT) ol[o] = f2bf(v - bf2f(hv));
    }
}

// ---------- router GEMM (proven round-3 structure, unchanged): 128x128, 256 thr ----------
// h = gelu_exact(x @ wr1 + br1), fp32-grade via 3-term bf16 split
__global__ __launch_bounds__(256) void k_rgemm(
    const ushort_t* __restrict__ A0, const ushort_t* __restrict__ B0,
    const ushort_t* __restrict__ A1, const ushort_t* __restrict__ B1,
    const ushort_t* __restrict__ A2, const ushort_t* __restrict__ B2,
    int K, int N, const float* __restrict__ bias, float* __restrict__ outF)
{
    __shared__ ushort_t lA[4096];
    __shared__ ushort_t lB[4096];
    int row0 = blockIdx.y * 128, col0 = blockIdx.x * 128;
    int tid = threadIdx.x, lane = tid & 63, wv = tid >> 6;
    int wr = wv >> 1, wc = wv & 1;
    int r15 = lane & 15, hq = lane >> 4;

    f32x4 z = {0.f, 0.f, 0.f, 0.f};
    f32x4 acc[4][4];
#pragma unroll
    for (int m = 0; m < 4; m++)
#pragma unroll
        for (int n = 0; n < 4; n++) acc[m][n] = z;

    int d0 = tid * 16, d1 = d0 + 4096;
    int u0 = swz(d0), u1 = swz(d1);
    int rA0 = u0 >> 6, ko0 = ((u0 >> 4) & 3) * 8;
    int rA1 = u1 >> 6, ko1 = ((u1 >> 4) & 3) * 8;
    char* ldA0 = (char*)lA + wv * 1024;
    char* ldA1 = (char*)lA + 4096 + wv * 1024;
    char* ldB0 = (char*)lB + wv * 1024;
    char* ldB1 = (char*)lB + 4096 + wv * 1024;

#pragma unroll
    for (int p = 0; p < 3; p++) {
        const ushort_t* A = (p == 0) ? A0 : ((p == 1) ? A1 : A2);
        const ushort_t* B = (p == 0) ? B0 : ((p == 1) ? B1 : B2);
        const ushort_t* Ab0 = A + (size_t)(row0 + rA0) * K + ko0;
        const ushort_t* Ab1 = A + (size_t)(row0 + rA1) * K + ko1;
        const ushort_t* Bb0 = B + (size_t)(col0 + rA0) * K + ko0;
        const ushort_t* Bb1 = B + (size_t)(col0 + rA1) * K + ko1;
        for (int kt = 0; kt < K; kt += 32) {
            gload16(Ab0 + kt, ldA0);
            gload16(Ab1 + kt, ldA1);
            gload16(Bb0 + kt, ldB0);
            gload16(Bb1 + kt, ldB1);
            __syncthreads();
            bf16x8 af[4], bfr[4];
#pragma unroll
            for (int m = 0; m < 4; m++) {
                int u = ((wr * 64 + m * 16 + r15) << 6) + (hq << 4);
                af[m] = *(const bf16x8*)((const char*)lA + swz(u));
            }
#pragma unroll
            for (int n = 0; n < 4; n++) {
                int u = ((wc * 64 + n * 16 + r15) << 6) + (hq << 4);
                bfr[n] = *(const bf16x8*)((const char*)lB + swz(u));
            }
#pragma unroll
            for (int m = 0; m < 4; m++)
#pragma unroll
                for (int n = 0; n < 4; n++)
                    acc[m][n] = __builtin_amdgcn_mfma_f32_16x16x32_bf16(af[m], bfr[n], acc[m][n], 0, 0, 0);
            __syncthreads();
        }
    }
#pragma unroll
    for (int m = 0; m < 4; m++)
#pragma unroll
        for (int q = 0; q < 4; q++) {
            int row = row0 + wr * 64 + m * 16 + hq * 4 + q;
#pragma unroll
            for (int n = 0; n < 4; n++) {
                int col = col0 + wc * 64 + n * 16 + r15;
                outF[(size_t)row * N + col] = gelu_exact(acc[m][n][q] + bias[col]);
            }
        }
}

// ---------- expert GEMM: 128x256 tile, BK=32, 512 thr, 2-phase dbuf pipeline ----------
// MODE 1: A=xh gathered by token list, B=w1T -> ghid = gate*gelu_fast(acc+b1) (bf16)
// MODE 2: A=ghid slots, B=w2T -> atomicAdd(out[token][col], acc)
template <int MODE>
__global__ __launch_bounds__(512, 4) void k_egemm(
    const ushort_t* __restrict__ A0, const ushort_t* __restrict__ B0,
    const float* __restrict__ bias, const float* __restrict__ gate,
    const int* __restrict__ idx, const int4* __restrict__ tiles,
    const int* __restrict__ meta,
    ushort_t* __restrict__ ghid, float* __restrict__ outA)
{
    constexpr int K = (MODE == 1) ? DM : DF;
    constexpr int NFULL = (MODE == 1) ? DF : DM;
    constexpr int NXT = NFULL / 256;
    constexpr int nwg = NXT * NYT_MAX;          // 2112 / 528, both % 8 == 0
    constexpr int q8 = nwg / 8;

    // bijective XCD chunking (m204, r==0), y-fastest within x-column:
    // each XCD keeps its B column-slices L2-resident and streams A panels.
    int bid = blockIdx.x;
    int wgid = (bid & 7) * q8 + (bid >> 3);
    int xt = wgid / NYT_MAX, yt = wgid % NYT_MAX;
    if (yt >= meta[0]) return;                  // block-uniform
    int4 ti = tiles[yt];
    int e = ti.x, rstart = ti.y, rows = ti.z, gbase = ti.w;
    int col0 = xt * 256;

    __shared__ ushort_t lA[2][4096];            // [buf][128 rows x 32 k], swizzled
    __shared__ ushort_t lB[2][8192];            // [buf][256 rows x 32 k], swizzled
    int tid = threadIdx.x, lane = tid & 63, wv = tid >> 6;
    int wr = wv >> 2, wc = wv & 3;              // 2M x 4N waves; per-wave 64x64 out
    int r15 = lane & 15, hq = lane >> 4;

    f32x4 z = {0.f, 0.f, 0.f, 0.f};
    f32x4 acc[4][4];
#pragma unroll
    for (int m = 0; m < 4; m++)
#pragma unroll
        for (int n = 0; n < 4; n++) acc[m][n] = z;

    // staging: thread tid stages A-chunk tid (byte tid*16 of lA) and B-chunks
    // tid, tid+512 (bytes tid*16, 8192+tid*16 of lB). Source = inverse-swizzle.
    int u = swz(tid * 16);
    int rA = u >> 6;                            // 0..127
    int ko = ((u >> 4) & 3) * 8;
    const ushort_t *Ab, *Bb0, *Bb1;
    if (MODE == 1) {
        int tok = idx[e * NTOK + rstart + imin(rA, rows - 1)];
        Ab = A0 + (size_t)tok * K + ko;
    } else {
        Ab = A0 + (size_t)(gbase + imin(rA, rows - 1)) * K + ko;
    }
    Bb0 = B0 + ((size_t)e * NFULL + col0 + rA) * K + ko;
    Bb1 = B0 + ((size_t)e * NFULL + col0 + 128 + rA) * K + ko;

    char* dstA = (char*)&lA[0][0];              // buffers are contiguous: [b] = +b*8192/+b*16384
    char* dstB = (char*)&lB[0][0];

    auto stage = [&](int b, int kt) {
        gload16(Ab + kt, dstA + b * 8192 + wv * 1024);
        gload16(Bb0 + kt, dstB + b * 16384 + wv * 1024);
        gload16(Bb1 + kt, dstB + b * 16384 + 8192 + wv * 1024);
    };
    auto compute = [&](int b) {
        const char* pa = (const char*)&lA[b][0];
        const char* pb = (const char*)&lB[b][0];
        bf16x8 af[4], bfr[4];
#pragma unroll
        for (int m = 0; m < 4; m++) {
            int ub = ((wr * 64 + m * 16 + r15) << 6) + (hq << 4);
            af[m] = *(const bf16x8*)(pa + swz(ub));
        }
#pragma unroll
        for (int n = 0; n < 4; n++) {
            int ub = ((wc * 64 + n * 16 + r15) << 6) + (hq << 4);
            bfr[n] = *(const bf16x8*)(pb + swz(ub));
        }
#pragma unroll
        for (int m = 0; m < 4; m++)
#pragma unroll
            for (int n = 0; n < 4; n++)
                acc[m][n] = __builtin_amdgcn_mfma_f32_16x16x32_bf16(af[m], bfr[n], acc[m][n], 0, 0, 0);
    };

    // 2-phase: issue next-tile loads BEFORE computing current tile (T3 minimum).
    // One __syncthreads per K-step (drains lgkmcnt+vmcnt -> race-free buffer swap).
    stage(0, 0);
    __syncthreads();
    int cur = 0;
    for (int kt = 32; kt < K; kt += 32) {
        stage(cur ^ 1, kt);
        compute(cur);
        __syncthreads();
        cur ^= 1;
    }
    compute(cur);

    // epilogue; C layout: col = lane&15, row = (lane>>4)*4 + q  [m89-verified]
    if (MODE == 1) {
#pragma unroll
        for (int m = 0; m < 4; m++)
#pragma unroll
            for (int q = 0; q < 4; q++) {
                int lr = wr * 64 + m * 16 + hq * 4 + q;
                if (lr < rows) {
                    int token = idx[e * NTOK + rstart + lr];
                    float g = gate[token * 4 + e];
                    size_t rb = (size_t)(gbase + lr) * NFULL;
#pragma unroll
                    for (int n = 0; n < 4; n++) {
                        int col = col0 + wc * 64 + n * 16 + r15;
                        float v = gelu_fast(acc[m][n][q] + bias[(size_t)e * NFULL + col]) * g;
                        ghid[rb + col] = f2bf(v);
                    }
                }
            }
    } else {
#pragma unroll
        for (int m = 0; m < 4; m++)
#pragma unroll
            for (int q = 0; q < 4; q++) {
                int lr = wr * 64 + m * 16 + hq * 4 + q;
                if (lr < rows) {
                    int token = idx[e * NTOK + rstart + lr];
#pragma unroll
                    for (int n = 0; n < 4; n++) {
                        int col = col0 + wc * 64 + n * 16 + r15;
                        atomicAdd(&outA[(size_t)token * NFULL + col], acc[m][n][q]);
                    }
                }
            }
    }
}

// ---------- router gate: fp32 logits, top-2, softmax, expert token lists ----------
__global__ __launch_bounds__(256) void k_gate(const float* __restrict__ h,
                                              const float* __restrict__ wr2,
                                              const float* __restrict__ br2,
                                              float* __restrict__ gate,
                                              int* __restrict__ cnt,
                                              int* __restrict__ idx) {
    int t = blockIdx.x * 4 + (threadIdx.x >> 6);
    int lane = threadIdx.x & 63;
    const float* hr = h + (size_t)t * DH;
    const float4* w4 = (const float4*)wr2;
    float gx = 0.f, gy = 0.f, gz = 0.f, gw = 0.f;
#pragma unroll
    for (int j = 0; j < 8; j++) {
        int k = lane * 8 + j;
        float hv = hr[k];
        float4 w = w4[k];
        gx += hv * w.x; gy += hv * w.y; gz += hv * w.z; gw += hv * w.w;
    }
#pragma unroll
    for (int off = 32; off > 0; off >>= 1) {
        gx += __shfl_xor(gx, off);
        gy += __shfl_xor(gy, off);
        gz += __shfl_xor(gz, off);
        gw += __shfl_xor(gw, off);
    }
    if (lane == 0) {
        float ls[4];
        ls[0] = gx + br2[0]; ls[1] = gy + br2[1]; ls[2] = gz + br2[2]; ls[3] = gw + br2[3];
        int i1 = 0; float m1 = ls[0];
#pragma unroll
        for (int i = 1; i < 4; i++) if (ls[i] > m1) { m1 = ls[i]; i1 = i; }
        int i2 = -1; float m2 = -1e30f;
#pragma unroll
        for (int i = 0; i < 4; i++) if (i != i1 && ls[i] > m2) { m2 = ls[i]; i2 = i; }
        float e0 = (ls[0] >= m2) ? expf(ls[0] - m1) : 0.f;
        float e1 = (ls[1] >= m2) ? expf(ls[1] - m1) : 0.f;
        float e2 = (ls[2] >= m2) ? expf(ls[2] - m1) : 0.f;
        float e3 = (ls[3] >= m2) ? expf(ls[3] - m1) : 0.f;
        float iz = 1.f / (e0 + e1 + e2 + e3);
        float4 g = {e0 * iz, e1 * iz, e2 * iz, e3 * iz};
        ((float4*)gate)[t] = g;
        int s0 = atomicAdd(&cnt[i1], 1);
        idx[i1 * NTOK + s0] = t;
        int s1 = atomicAdd(&cnt[i2], 1);
        idx[i2 * NTOK + s1] = t;
    }
}

// ---------- tile table over per-expert lists ----------
__global__ void k_tiles(const int* __restrict__ cnt, int4* __restrict__ tiles,
                        int* __restrict__ meta) {
    if (threadIdx.x != 0 || blockIdx.x != 0) return;
    int base = 0, nt = 0;
    for (int e = 0; e < NE; e++) {
        int c = cnt[e];
        for (int r = 0; r < c; r += 128) {
            int4 ti;
            ti.x = e; ti.y = r; ti.z = (c - r < 128) ? (c - r) : 128; ti.w = base + r;
            tiles[nt++] = ti;
        }
        base += c;
    }
    meta[0] = nt;
}

// ---------- out init: out[t][d] = sum_e gate[t][e] * b2[e][d] ----------
__global__ __launch_bounds__(256) void k_init_out(const float* __restrict__ gate,
                                                  const float* __restrict__ b2,
                                                  float* __restrict__ out) {
    int i = blockIdx.x * 256 + threadIdx.x;
    int t = i >> 8;
    int c4 = i & 255;
    float4 g = ((const float4*)gate)[t];
    const float4* b = (const float4*)b2;
    float4 v0 = b[c4], v1 = b[256 + c4], v2 = b[512 + c4], v3 = b[768 + c4];
    float4 o;
    o.x = g.x * v0.x + g.y * v1.x + g.z * v2.x + g.w * v3.x;
    o.y = g.x * v0.y + g.y * v1.y + g.z * v2.y + g.w * v3.y;
    o.z = g.x * v0.z + g.y * v1.z + g.z * v2.z + g.w * v3.z;
    o.w = g.x * v0.w + g.y * v1.w + g.z * v2.w + g.w * v3.w;
    ((float4*)out)[i] = o;
}

extern "C" void kernel_launch(void* const* d_in, const int* in_sizes, int n_in,
                              void* d_out, int out_size, void* d_ws, size_t ws_size,
                              hipStream_t stream) {
    const float* x   = (const float*)d_in[0];
    const float* w1  = (const float*)d_in[1];
    const float* b1  = (const float*)d_in[2];
    const float* w2  = (const float*)d_in[3];
    const float* b2  = (const float*)d_in[4];
    const float* wr1 = (const float*)d_in[5];
    const float* br1 = (const float*)d_in[6];
    const float* wr2 = (const float*)d_in[7];
    const float* br2 = (const float*)d_in[8];
    float* out  = (float*)d_out;
    float* gate = out + (size_t)NTOK * DM;

    char* p = (char*)d_ws;
    auto take = [&](size_t bytes) { char* r = p; p += (bytes + 255) & ~(size_t)255; return r; };
    ushort_t* xh    = (ushort_t*)take((size_t)NTOK * DM * 2);
    ushort_t* w1T   = (ushort_t*)take((size_t)NE * DF * DM * 2);   // [e][N=DF][K=DM]
    ushort_t* w2T   = (ushort_t*)take((size_t)NE * DM * DF * 2);   // [e][N=DM][K=DF]
    ushort_t* wr1Th = (ushort_t*)take((size_t)DH * DM * 2);        // [N=DH][K=DM]
    ushort_t* wr1Tl = (ushort_t*)take((size_t)DH * DM * 2);
    int*      cnt   = (int*)take(64);
    int*      idx   = (int*)take((size_t)NE * NTOK * 4);
    int4*     tiles = (int4*)take(144 * 16);
    int*      meta  = (int*)take(64);
    char*     region = take((size_t)SLOTS * DF * 2);               // ghid overlays xl+h
    ushort_t* xl    = (ushort_t*)region;
    float*    h     = (float*)(region + (size_t)NTOK * DM * 2);
    ushort_t* ghid  = (ushort_t*)region;                           // [slot][DF]

    hipMemsetAsync(cnt, 0, 64, stream);

    // prep
    k_cast_split<<<NTOK * DM / 4 / 256, 256, 0, stream>>>(x, xh, xl, NTOK * DM / 4);
    k_tcast<false><<<dim3(DF / 64, DM / 64, NE), 256, 0, stream>>>(w1, w1T, nullptr, DM, DF);
    k_tcast<false><<<dim3(DM / 64, DF / 64, NE), 256, 0, stream>>>(w2, w2T, nullptr, DF, DM);
    k_tcast<true ><<<dim3(DH / 64, DM / 64, 1),  256, 0, stream>>>(wr1, wr1Th, wr1Tl, DM, DH);

    // router
    k_rgemm<<<dim3(DH / 128, NTOK / 128), 256, 0, stream>>>(
        xh, wr1Th, xh, wr1Tl, xl, wr1Th, DM, DH, br1, h);
    k_gate<<<NTOK / 4, 256, 0, stream>>>(h, wr2, br2, gate, cnt, idx);
    k_tiles<<<1, 64, 0, stream>>>(cnt, tiles, meta);
    k_init_out<<<NTOK * DM / 4 / 256, 256, 0, stream>>>(gate, b2, out);

    // sparse expert GEMMs (top-2: 16384 slot-rows, <=132 row-tiles)
    k_egemm<1><<<(DF / 256) * NYT_MAX, 512, 0, stream>>>(
        xh, w1T, b1, gate, idx, tiles, meta, ghid, nullptr);
    k_egemm<2><<<(DM / 256) * NYT_MAX, 512, 0, stream>>>(
        ghid, w2T, nullptr, gate, idx, tiles, meta, nullptr, out);
}

// Round 5
// 941.891 us; speedup vs baseline: 1.2946x; 1.0075x over previous
//
#include <hip/hip_runtime.h>

#define NTOK 8192
#define DM 1024
#define DF 4096
#define DH 512
#define NE 4
#define SLOTS (NTOK * 2)
#define NYT_MAX 132

typedef unsigned short ushort_t;
typedef short bf16x8 __attribute__((ext_vector_type(8)));
typedef float f32x4 __attribute__((ext_vector_type(4)));

__device__ __forceinline__ unsigned short f2bf(float f) {
    unsigned int u = __float_as_uint(f);
    u += 0x7FFFu + ((u >> 16) & 1u);   // RNE
    return (unsigned short)(u >> 16);
}
__device__ __forceinline__ float bf2f(unsigned short h) {
    return __uint_as_float(((unsigned int)h) << 16);
}
__device__ __forceinline__ float gelu_exact(float x) {
    return 0.5f * x * (1.0f + erff(x * 0.7071067811865476f));
}
__device__ __forceinline__ float gelu_fast(float x) {
    float u = 1.5957691216057308f * (x + 0.044715f * x * x * x);
    return x / (1.0f + __expf(-u));
}
__device__ __forceinline__ void gload16(const void* g, void* l) {
    __builtin_amdgcn_global_load_lds((__attribute__((address_space(1))) void*)(g),
                                     (__attribute__((address_space(3))) void*)(l), 16, 0, 0);
}
// LDS bank swizzle: XOR byte bits 4-5 with row bits 1-2 (byte bits 7-8). Involution.
// Verified round 3/4: SQ_LDS_BANK_CONFLICT == 0.
__device__ __forceinline__ int swz(int b) { return b ^ (((b >> 7) & 3) << 4); }
__device__ __forceinline__ int imin(int a, int b) { return a < b ? a : b; }

#define WAIT_VM(N) asm volatile("s_waitcnt vmcnt(" #N ")" ::: "memory")
#define WAIT_LGKM0() asm volatile("s_waitcnt lgkmcnt(0)" ::: "memory")
#define SBAR() __builtin_amdgcn_s_barrier()
#define SCHED0() __builtin_amdgcn_sched_barrier(0)

// ---------- prep: x -> (xh, xl) bf16 split ----------
__global__ __launch_bounds__(256) void k_cast_split(const float* __restrict__ in,
                                                    ushort_t* __restrict__ hi,
                                                    ushort_t* __restrict__ lo, int n4) {
    int i = blockIdx.x * 256 + threadIdx.x;
    if (i >= n4) return;
    float4 v = ((const float4*)in)[i];
    ushort4 h, l;
    h.x = f2bf(v.x); l.x = f2bf(v.x - bf2f(h.x));
    h.y = f2bf(v.y); l.y = f2bf(v.y - bf2f(h.y));
    h.z = f2bf(v.z); l.z = f2bf(v.z - bf2f(h.z));
    h.w = f2bf(v.w); l.w = f2bf(v.w - bf2f(h.w));
    ((ushort4*)hi)[i] = h;
    ((ushort4*)lo)[i] = l;
}

// ---------- prep: [E][K][N] fp32 -> [E][N][K] bf16 (optional split) ----------
template <bool SPLIT>
__global__ __launch_bounds__(256) void k_tcast(const float* __restrict__ in,
                                               ushort_t* __restrict__ oh,
                                               ushort_t* __restrict__ ol, int K, int N) {
    __shared__ float t[64][65];
    size_t base = (size_t)blockIdx.z * K * N;
    const float* src = in + base;
    int k0 = blockIdx.y * 64, n0 = blockIdx.x * 64;
    int tx = threadIdx.x & 63, ty = threadIdx.x >> 6;
#pragma unroll
    for (int i = 0; i < 16; i++) {
        int r = ty + i * 4;
        t[r][tx] = src[(size_t)(k0 + r) * N + n0 + tx];
    }
    __syncthreads();
#pragma unroll
    for (int i = 0; i < 16; i++) {
        int nn = ty + i * 4;
        float v = t[tx][nn];
        unsigned short hv = f2bf(v);
        size_t o = base + (size_t)(n0 + nn) * K + k0 + tx;
        oh[o] = hv;
        if (SPLIT) ol[o] = f2bf(v - bf2f(hv));
    }
}

// ---------- router GEMM: 128x128, 256 thr, 3-deep counted-vmcnt pipeline ----------
// h = gelu_exact(x @ wr1 + br1), fp32-grade via 3-term bf16 split (3 passes)
__global__ __launch_bounds__(256) void k_rgemm(
    const ushort_t* __restrict__ A0, const ushort_t* __restrict__ B0,
    const ushort_t* __restrict__ A1, const ushort_t* __restrict__ B1,
    const ushort_t* __restrict__ A2, const ushort_t* __restrict__ B2,
    int K, int N, const float* __restrict__ bias, float* __restrict__ outF)
{
    __shared__ ushort_t lA[3][4096];   // 3 bufs x 8KB, bank-swizzled
    __shared__ ushort_t lB[3][4096];
    int row0 = blockIdx.y * 128, col0 = blockIdx.x * 128;
    int tid = threadIdx.x, lane = tid & 63, wv = tid >> 6;
    int wr = wv >> 1, wc = wv & 1;
    int r15 = lane & 15, hq = lane >> 4;

    f32x4 z = {0.f, 0.f, 0.f, 0.f};
    f32x4 acc[4][4];
#pragma unroll
    for (int m = 0; m < 4; m++)
#pragma unroll
        for (int n = 0; n < 4; n++) acc[m][n] = z;

    int d0 = tid * 16, d1 = d0 + 4096;
    int u0 = swz(d0), u1 = swz(d1);
    int rA0 = u0 >> 6, ko0 = ((u0 >> 4) & 3) * 8;
    int rA1 = u1 >> 6, ko1 = ((u1 >> 4) & 3) * 8;
    int nstep = K / 32;

#pragma unroll 1
    for (int p = 0; p < 3; p++) {
        const ushort_t* A = (p == 0) ? A0 : ((p == 1) ? A1 : A2);
        const ushort_t* B = (p == 0) ? B0 : ((p == 1) ? B1 : B2);
        const ushort_t* Ab0 = A + (size_t)(row0 + rA0) * K + ko0;
        const ushort_t* Ab1 = A + (size_t)(row0 + rA1) * K + ko1;
        const ushort_t* Bb0 = B + (size_t)(col0 + rA0) * K + ko0;
        const ushort_t* Bb1 = B + (size_t)(col0 + rA1) * K + ko1;

        auto stage = [&](int b, int s) {
            int kt = s * 32;
            char* la = (char*)lA + b * 8192;
            char* lb = (char*)lB + b * 8192;
            gload16(Ab0 + kt, la + wv * 1024);
            gload16(Ab1 + kt, la + 4096 + wv * 1024);
            gload16(Bb0 + kt, lb + wv * 1024);
            gload16(Bb1 + kt, lb + 4096 + wv * 1024);
        };
        auto compute = [&](int b) {
            const char* pa = (const char*)lA + b * 8192;
            const char* pb = (const char*)lB + b * 8192;
            bf16x8 af[4], bfr[4];
#pragma unroll
            for (int m = 0; m < 4; m++)
                af[m] = *(const bf16x8*)(pa + swz(((wr * 64 + m * 16 + r15) << 6) + (hq << 4)));
#pragma unroll
            for (int n = 0; n < 4; n++)
                bfr[n] = *(const bf16x8*)(pb + swz(((wc * 64 + n * 16 + r15) << 6) + (hq << 4)));
            __builtin_amdgcn_s_setprio(1);
#pragma unroll
            for (int m = 0; m < 4; m++)
#pragma unroll
                for (int n = 0; n < 4; n++)
                    acc[m][n] = __builtin_amdgcn_mfma_f32_16x16x32_bf16(af[m], bfr[n], acc[m][n], 0, 0, 0);
            __builtin_amdgcn_s_setprio(0);
        };

        stage(0, 0); stage(1, 1); stage(2, 2);
        int cur = 0;
#pragma unroll 1
        for (int s = 0; s < nstep - 3; s++) {
            WAIT_VM(8); SBAR(); SCHED0();
            compute(cur);
            WAIT_LGKM0(); SCHED0(); SBAR(); SCHED0();
            stage(cur, s + 3);
            cur = (cur == 2) ? 0 : cur + 1;
        }
        WAIT_VM(8); SBAR(); SCHED0();
        compute(cur); cur = (cur == 2) ? 0 : cur + 1;
        WAIT_VM(4); SBAR(); SCHED0();
        compute(cur); cur = (cur == 2) ? 0 : cur + 1;
        WAIT_VM(0); SBAR(); SCHED0();
        compute(cur);
        // pass boundary: all reads done before next pass restages buffers
        WAIT_LGKM0(); SCHED0(); SBAR(); SCHED0();
    }

#pragma unroll
    for (int m = 0; m < 4; m++)
#pragma unroll
        for (int q = 0; q < 4; q++) {
            int row = row0 + wr * 64 + m * 16 + hq * 4 + q;
#pragma unroll
            for (int n = 0; n < 4; n++) {
                int col = col0 + wc * 64 + n * 16 + r15;
                outF[(size_t)row * N + col] = gelu_exact(acc[m][n][q] + bias[col]);
            }
        }
}

// ---------- expert GEMM: 128x256, 512 thr, 3-deep counted-vmcnt pipeline ----------
// MODE 1: A=xh gathered by token list, B=w1T -> ghid = gate*gelu_fast(acc+b1) (bf16)
// MODE 2: A=ghid slots, B=w2T -> atomicAdd(out[token][col], acc)
template <int MODE>
__global__ __launch_bounds__(512, 4) void k_egemm(
    const ushort_t* __restrict__ A0, const ushort_t* __restrict__ B0,
    const float* __restrict__ bias, const float* __restrict__ gate,
    const int* __restrict__ idx, const int4* __restrict__ tiles,
    const int* __restrict__ meta,
    ushort_t* __restrict__ ghid, float* __restrict__ outA)
{
    constexpr int K = (MODE == 1) ? DM : DF;
    constexpr int NFULL = (MODE == 1) ? DF : DM;
    constexpr int NXT = NFULL / 256;
    constexpr int nwg = NXT * NYT_MAX;
    constexpr int q8 = nwg / 8;
    constexpr int NSTEP = K / 32;

    // bijective XCD chunking (m204, r==0), y-fastest within x-column
    int bid = blockIdx.x;
    int wgid = (bid & 7) * q8 + (bid >> 3);
    int xt = wgid / NYT_MAX, yt = wgid % NYT_MAX;
    if (yt >= meta[0]) return;                  // block-uniform
    int4 ti = tiles[yt];
    int e = ti.x, rstart = ti.y, rows = ti.z, gbase = ti.w;
    int col0 = xt * 256;

    __shared__ ushort_t lA[3][4096];            // 3 x 8KB
    __shared__ ushort_t lB[3][8192];            // 3 x 16KB  (72KB total)
    int tid = threadIdx.x, lane = tid & 63, wv = tid >> 6;
    int wr = wv >> 2, wc = wv & 3;              // 2M x 4N waves; 64x64 out each
    int r15 = lane & 15, hq = lane >> 4;

    f32x4 z = {0.f, 0.f, 0.f, 0.f};
    f32x4 acc[4][4];
#pragma unroll
    for (int m = 0; m < 4; m++)
#pragma unroll
        for (int n = 0; n < 4; n++) acc[m][n] = z;

    int u = swz(tid * 16);
    int rA = u >> 6;
    int ko = ((u >> 4) & 3) * 8;
    const ushort_t *Ab, *Bb0, *Bb1;
    if (MODE == 1) {
        int tok = idx[e * NTOK + rstart + imin(rA, rows - 1)];
        Ab = A0 + (size_t)tok * K + ko;
    } else {
        Ab = A0 + (size_t)(gbase + imin(rA, rows - 1)) * K + ko;
    }
    Bb0 = B0 + ((size_t)e * NFULL + col0 + rA) * K + ko;
    Bb1 = B0 + ((size_t)e * NFULL + col0 + 128 + rA) * K + ko;

    auto stage = [&](int b, int s) {
        int kt = s * 32;
        gload16(Ab + kt, (char*)lA + b * 8192 + wv * 1024);
        gload16(Bb0 + kt, (char*)lB + b * 16384 + wv * 1024);
        gload16(Bb1 + kt, (char*)lB + b * 16384 + 8192 + wv * 1024);
    };
    auto compute = [&](int b) {
        const char* pa = (const char*)lA + b * 8192;
        const char* pb = (const char*)lB + b * 16384;
        bf16x8 af[4], bfr[4];
#pragma unroll
        for (int m = 0; m < 4; m++)
            af[m] = *(const bf16x8*)(pa + swz(((wr * 64 + m * 16 + r15) << 6) + (hq << 4)));
#pragma unroll
        for (int n = 0; n < 4; n++)
            bfr[n] = *(const bf16x8*)(pb + swz(((wc * 64 + n * 16 + r15) << 6) + (hq << 4)));
        __builtin_amdgcn_s_setprio(1);
#pragma unroll
        for (int m = 0; m < 4; m++)
#pragma unroll
            for (int n = 0; n < 4; n++)
                acc[m][n] = __builtin_amdgcn_mfma_f32_16x16x32_bf16(af[m], bfr[n], acc[m][n], 0, 0, 0);
        __builtin_amdgcn_s_setprio(0);
    };

    stage(0, 0); stage(1, 1); stage(2, 2);
    int cur = 0;
#pragma unroll 1
    for (int s = 0; s < NSTEP - 3; s++) {
        WAIT_VM(6); SBAR(); SCHED0();
        compute(cur);
        WAIT_LGKM0(); SCHED0(); SBAR(); SCHED0();
        stage(cur, s + 3);
        cur = (cur == 2) ? 0 : cur + 1;
    }
    WAIT_VM(6); SBAR(); SCHED0();
    compute(cur); cur = (cur == 2) ? 0 : cur + 1;
    WAIT_VM(3); SBAR(); SCHED0();
    compute(cur); cur = (cur == 2) ? 0 : cur + 1;
    WAIT_VM(0); SBAR(); SCHED0();
    compute(cur);

    // epilogue; C layout: col = lane&15, row = (lane>>4)*4 + q  [m89-verified]
    if (MODE == 1) {
#pragma unroll
        for (int m = 0; m < 4; m++)
#pragma unroll
            for (int q = 0; q < 4; q++) {
                int lr = wr * 64 + m * 16 + hq * 4 + q;
                if (lr < rows) {
                    int token = idx[e * NTOK + rstart + lr];
                    float g = gate[token * 4 + e];
                    size_t rb = (size_t)(gbase + lr) * NFULL;
#pragma unroll
                    for (int n = 0; n < 4; n++) {
                        int col = col0 + wc * 64 + n * 16 + r15;
                        float v = gelu_fast(acc[m][n][q] + bias[(size_t)e * NFULL + col]) * g;
                        ghid[rb + col] = f2bf(v);
                    }
                }
            }
    } else {
#pragma unroll
        for (int m = 0; m < 4; m++)
#pragma unroll
            for (int q = 0; q < 4; q++) {
                int lr = wr * 64 + m * 16 + hq * 4 + q;
                if (lr < rows) {
                    int token = idx[e * NTOK + rstart + lr];
#pragma unroll
                    for (int n = 0; n < 4; n++) {
                        int col = col0 + wc * 64 + n * 16 + r15;
                        atomicAdd(&outA[(size_t)token * NFULL + col], acc[m][n][q]);
                    }
                }
            }
    }
}

// ---------- router gate: fp32 logits, top-2, softmax, expert token lists ----------
__global__ __launch_bounds__(256) void k_gate(const float* __restrict__ h,
                                              const float* __restrict__ wr2,
                                              const float* __restrict__ br2,
                                              float* __restrict__ gate,
                                              int* __restrict__ cnt,
                                              int* __restrict__ idx) {
    int t = blockIdx.x * 4 + (threadIdx.x >> 6);
    int lane = threadIdx.x & 63;
    const float* hr = h + (size_t)t * DH;
    const float4* w4 = (const float4*)wr2;
    float gx = 0.f, gy = 0.f, gz = 0.f, gw = 0.f;
#pragma unroll
    for (int j = 0; j < 8; j++) {
        int k = lane * 8 + j;
        float hv = hr[k];
        float4 w = w4[k];
        gx += hv * w.x; gy += hv * w.y; gz += hv * w.z; gw += hv * w.w;
    }
#pragma unroll
    for (int off = 32; off > 0; off >>= 1) {
        gx += __shfl_xor(gx, off);
        gy += __shfl_xor(gy, off);
        gz += __shfl_xor(gz, off);
        gw += __shfl_xor(gw, off);
    }
    if (lane == 0) {
        float ls[4];
        ls[0] = gx + br2[0]; ls[1] = gy + br2[1]; ls[2] = gz + br2[2]; ls[3] = gw + br2[3];
        int i1 = 0; float m1 = ls[0];
#pragma unroll
        for (int i = 1; i < 4; i++) if (ls[i] > m1) { m1 = ls[i]; i1 = i; }
        int i2 = -1; float m2 = -1e30f;
#pragma unroll
        for (int i = 0; i < 4; i++) if (i != i1 && ls[i] > m2) { m2 = ls[i]; i2 = i; }
        float e0 = (ls[0] >= m2) ? expf(ls[0] - m1) : 0.f;
        float e1 = (ls[1] >= m2) ? expf(ls[1] - m1) : 0.f;
        float e2 = (ls[2] >= m2) ? expf(ls[2] - m1) : 0.f;
        float e3 = (ls[3] >= m2) ? expf(ls[3] - m1) : 0.f;
        float iz = 1.f / (e0 + e1 + e2 + e3);
        float4 g = {e0 * iz, e1 * iz, e2 * iz, e3 * iz};
        ((float4*)gate)[t] = g;
        int s0 = atomicAdd(&cnt[i1], 1);
        idx[i1 * NTOK + s0] = t;
        int s1 = atomicAdd(&cnt[i2], 1);
        idx[i2 * NTOK + s1] = t;
    }
}

// ---------- tile table over per-expert lists ----------
__global__ void k_tiles(const int* __restrict__ cnt, int4* __restrict__ tiles,
                        int* __restrict__ meta) {
    if (threadIdx.x != 0 || blockIdx.x != 0) return;
    int base = 0, nt = 0;
    for (int e = 0; e < NE; e++) {
        int c = cnt[e];
        for (int r = 0; r < c; r += 128) {
            int4 ti;
            ti.x = e; ti.y = r; ti.z = (c - r < 128) ? (c - r) : 128; ti.w = base + r;
            tiles[nt++] = ti;
        }
        base += c;
    }
    meta[0] = nt;
}

// ---------- out init: out[t][d] = sum_e gate[t][e] * b2[e][d] ----------
__global__ __launch_bounds__(256) void k_init_out(const float* __restrict__ gate,
                                                  const float* __restrict__ b2,
                                                  float* __restrict__ out) {
    int i = blockIdx.x * 256 + threadIdx.x;
    int t = i >> 8;
    int c4 = i & 255;
    float4 g = ((const float4*)gate)[t];
    const float4* b = (const float4*)b2;
    float4 v0 = b[c4], v1 = b[256 + c4], v2 = b[512 + c4], v3 = b[768 + c4];
    float4 o;
    o.x = g.x * v0.x + g.y * v1.x + g.z * v2.x + g.w * v3.x;
    o.y = g.x * v0.y + g.y * v1.y + g.z * v2.y + g.w * v3.y;
    o.z = g.x * v0.z + g.y * v1.z + g.z * v2.z + g.w * v3.z;
    o.w = g.x * v0.w + g.y * v1.w + g.z * v2.w + g.w * v3.w;
    ((float4*)out)[i] = o;
}

extern "C" void kernel_launch(void* const* d_in, const int* in_sizes, int n_in,
                              void* d_out, int out_size, void* d_ws, size_t ws_size,
                              hipStream_t stream) {
    const float* x   = (const float*)d_in[0];
    const float* w1  = (const float*)d_in[1];
    const float* b1  = (const float*)d_in[2];
    const float* w2  = (const float*)d_in[3];
    const float* b2  = (const float*)d_in[4];
    const float* wr1 = (const float*)d_in[5];
    const float* br1 = (const float*)d_in[6];
    const float* wr2 = (const float*)d_in[7];
    const float* br2 = (const float*)d_in[8];
    float* out  = (float*)d_out;
    float* gate = out + (size_t)NTOK * DM;

    char* p = (char*)d_ws;
    auto take = [&](size_t bytes) { char* r = p; p += (bytes + 255) & ~(size_t)255; return r; };
    ushort_t* xh    = (ushort_t*)take((size_t)NTOK * DM * 2);
    ushort_t* w1T   = (ushort_t*)take((size_t)NE * DF * DM * 2);   // [e][N=DF][K=DM]
    ushort_t* w2T   = (ushort_t*)take((size_t)NE * DM * DF * 2);   // [e][N=DM][K=DF]
    ushort_t* wr1Th = (ushort_t*)take((size_t)DH * DM * 2);        // [N=DH][K=DM]
    ushort_t* wr1Tl = (ushort_t*)take((size_t)DH * DM * 2);
    int*      cnt   = (int*)take(64);
    int*      idx   = (int*)take((size_t)NE * NTOK * 4);
    int4*     tiles = (int4*)take(144 * 16);
    int*      meta  = (int*)take(64);
    char*     region = take((size_t)SLOTS * DF * 2);               // ghid overlays xl+h
    ushort_t* xl    = (ushort_t*)region;
    float*    h     = (float*)(region + (size_t)NTOK * DM * 2);
    ushort_t* ghid  = (ushort_t*)region;                           // [slot][DF]

    hipMemsetAsync(cnt, 0, 64, stream);

    // prep
    k_cast_split<<<NTOK * DM / 4 / 256, 256, 0, stream>>>(x, xh, xl, NTOK * DM / 4);
    k_tcast<false><<<dim3(DF / 64, DM / 64, NE), 256, 0, stream>>>(w1, w1T, nullptr, DM, DF);
    k_tcast<false><<<dim3(DM / 64, DF / 64, NE), 256, 0, stream>>>(w2, w2T, nullptr, DF, DM);
    k_tcast<true ><<<dim3(DH / 64, DM / 64, 1),  256, 0, stream>>>(wr1, wr1Th, wr1Tl, DM, DH);

    // router
    k_rgemm<<<dim3(DH / 128, NTOK / 128), 256, 0, stream>>>(
        xh, wr1Th, xh, wr1Tl, xl, wr1Th, DM, DH, br1, h);
    k_gate<<<NTOK / 4, 256, 0, stream>>>(h, wr2, br2, gate, cnt, idx);
    k_tiles<<<1, 64, 0, stream>>>(cnt, tiles, meta);
    k_init_out<<<NTOK * DM / 4 / 256, 256, 0, stream>>>(gate, b2, out);

    // sparse expert GEMMs (top-2: 16384 slot-rows, <=132 row-tiles)
    k_egemm<1><<<(DF / 256) * NYT_MAX, 512, 0, stream>>>(
        xh, w1T, b1, gate, idx, tiles, meta, ghid, nullptr);
    k_egemm<2><<<(DM / 256) * NYT_MAX, 512, 0, stream>>>(
        ghid, w2T, nullptr, gate, idx, tiles, meta, nullptr, out);
}

// Round 7
// 880.799 us; speedup vs baseline: 1.3844x; 1.0694x over previous
//
#include <hip/hip_runtime.h>

#define NTOK 8192
#define DM 1024
#define DF 4096
#define DH 512
#define NE 4
#define SLOTS (NTOK * 2)
#define NYT_MAX 132

typedef unsigned short ushort_t;
typedef short bf16x8 __attribute__((ext_vector_type(8)));
typedef float f32x4 __attribute__((ext_vector_type(4)));

__device__ __forceinline__ unsigned short f2bf(float f) {
    unsigned int u = __float_as_uint(f);
    u += 0x7FFFu + ((u >> 16) & 1u);   // RNE
    return (unsigned short)(u >> 16);
}
__device__ __forceinline__ float bf2f(unsigned short h) {
    return __uint_as_float(((unsigned int)h) << 16);
}
__device__ __forceinline__ float gelu_exact(float x) {
    return 0.5f * x * (1.0f + erff(x * 0.7071067811865476f));
}
__device__ __forceinline__ float gelu_fast(float x) {
    float u = 1.5957691216057308f * (x + 0.044715f * x * x * x);
    return x / (1.0f + __expf(-u));
}
__device__ __forceinline__ void gload16(const void* g, void* l) {
    __builtin_amdgcn_global_load_lds((__attribute__((address_space(1))) void*)(g),
                                     (__attribute__((address_space(3))) void*)(l), 16, 0, 0);
}
// LDS bank swizzle (verified: 0 conflicts). Involution on local byte offset.
// NOTE: swz only permutes bits 4-5 keyed on bits 7-8, so for region offsets that are
// multiples of 4096: swz(off + b) = off + swz(b)  ->  swz(d)>>6 INCLUDES the region rows.
__device__ __forceinline__ int swz(int b) { return b ^ (((b >> 7) & 3) << 4); }
__device__ __forceinline__ int imin(int a, int b) { return a < b ? a : b; }

#define WAIT_VM(N) asm volatile("s_waitcnt vmcnt(" #N ")" ::: "memory")
#define WAIT_LGKM0() asm volatile("s_waitcnt lgkmcnt(0)" ::: "memory")
#define SBAR() __builtin_amdgcn_s_barrier()
#define SCHED0() __builtin_amdgcn_sched_barrier(0)

// ---------- prep: x -> (xh, xl) bf16 split ----------
__global__ __launch_bounds__(256) void k_cast_split(const float* __restrict__ in,
                                                    ushort_t* __restrict__ hi,
                                                    ushort_t* __restrict__ lo, int n4) {
    int i = blockIdx.x * 256 + threadIdx.x;
    if (i >= n4) return;
    float4 v = ((const float4*)in)[i];
    ushort4 h, l;
    h.x = f2bf(v.x); l.x = f2bf(v.x - bf2f(h.x));
    h.y = f2bf(v.y); l.y = f2bf(v.y - bf2f(h.y));
    h.z = f2bf(v.z); l.z = f2bf(v.z - bf2f(h.z));
    h.w = f2bf(v.w); l.w = f2bf(v.w - bf2f(h.w));
    ((ushort4*)hi)[i] = h;
    ((ushort4*)lo)[i] = l;
}

// ---------- prep: [E][K][N] fp32 -> [E][N][K] bf16 (optional split) ----------
template <bool SPLIT>
__global__ __launch_bounds__(256) void k_tcast(const float* __restrict__ in,
                                               ushort_t* __restrict__ oh,
                                               ushort_t* __restrict__ ol, int K, int N) {
    __shared__ float t[64][65];
    size_t base = (size_t)blockIdx.z * K * N;
    const float* src = in + base;
    int k0 = blockIdx.y * 64, n0 = blockIdx.x * 64;
    int tx = threadIdx.x & 63, ty = threadIdx.x >> 6;
#pragma unroll
    for (int i = 0; i < 16; i++) {
        int r = ty + i * 4;
        t[r][tx] = src[(size_t)(k0 + r) * N + n0 + tx];
    }
    __syncthreads();
#pragma unroll
    for (int i = 0; i < 16; i++) {
        int nn = ty + i * 4;
        float v = t[tx][nn];
        unsigned short hv = f2bf(v);
        size_t o = base + (size_t)(n0 + nn) * K + k0 + tx;
        oh[o] = hv;
        if (SPLIT) ol[o] = f2bf(v - bf2f(hv));
    }
}

// ---------- router GEMM: 128x128, pass split across grid.z, atomicAdd raw h ----------
__global__ __launch_bounds__(256, 3) void k_rgemm(
    const ushort_t* __restrict__ A0, const ushort_t* __restrict__ B0,
    const ushort_t* __restrict__ A1, const ushort_t* __restrict__ B1,
    const ushort_t* __restrict__ A2, const ushort_t* __restrict__ B2,
    float* __restrict__ hraw)
{
    constexpr int K = DM, N = DH;
    __shared__ ushort_t lA[3][4096];
    __shared__ ushort_t lB[3][4096];
    int row0 = blockIdx.y * 128, col0 = blockIdx.x * 128;
    int p = blockIdx.z;
    const ushort_t* A = (p == 0) ? A0 : ((p == 1) ? A1 : A2);
    const ushort_t* B = (p == 0) ? B0 : ((p == 1) ? B1 : B2);
    int tid = threadIdx.x, lane = tid & 63, wv = tid >> 6;
    int wr = wv >> 1, wc = wv & 1;
    int r15 = lane & 15, hq = lane >> 4;

    f32x4 z = {0.f, 0.f, 0.f, 0.f};
    f32x4 acc[4][4];
#pragma unroll
    for (int m = 0; m < 4; m++)
#pragma unroll
        for (int n = 0; n < 4; n++) acc[m][n] = z;

    int d0 = tid * 16, d1 = d0 + 4096;
    int u0 = swz(d0), u1 = swz(d1);
    int rA0 = u0 >> 6, ko0 = ((u0 >> 4) & 3) * 8;
    int rA1 = (u1 >> 6) & 63, ko1 = ((u1 >> 4) & 3) * 8;   // local row within 2nd 4KB region
    // (256 threads, lA region layout: [0,4096)=rows 0-63, [4096,8192)=rows 64-127)
    const ushort_t* Ab0 = A + (size_t)(row0 + rA0) * K + ko0;
    const ushort_t* Ab1 = A + (size_t)(row0 + 64 + rA1) * K + ko1;
    const ushort_t* Bb0 = B + (size_t)(col0 + rA0) * K + ko0;
    const ushort_t* Bb1 = B + (size_t)(col0 + 64 + rA1) * K + ko1;

    auto stage = [&](int b, int s) {
        int kt = s * 32;
        char* la = (char*)lA + b * 8192;
        char* lb = (char*)lB + b * 8192;
        gload16(Ab0 + kt, la + wv * 1024);
        gload16(Ab1 + kt, la + 4096 + wv * 1024);
        gload16(Bb0 + kt, lb + wv * 1024);
        gload16(Bb1 + kt, lb + 4096 + wv * 1024);
    };
    auto compute = [&](int b) {
        const char* pa = (const char*)lA + b * 8192;
        const char* pb = (const char*)lB + b * 8192;
        bf16x8 af[4], bfr[4];
#pragma unroll
        for (int m = 0; m < 4; m++)
            af[m] = *(const bf16x8*)(pa + swz(((wr * 64 + m * 16 + r15) << 6) + (hq << 4)));
#pragma unroll
        for (int n = 0; n < 4; n++)
            bfr[n] = *(const bf16x8*)(pb + swz(((wc * 64 + n * 16 + r15) << 6) + (hq << 4)));
        __builtin_amdgcn_s_setprio(1);
#pragma unroll
        for (int m = 0; m < 4; m++)
#pragma unroll
            for (int n = 0; n < 4; n++)
                acc[m][n] = __builtin_amdgcn_mfma_f32_16x16x32_bf16(af[m], bfr[n], acc[m][n], 0, 0, 0);
        __builtin_amdgcn_s_setprio(0);
    };

    stage(0, 0); stage(1, 1); stage(2, 2);
    int cur = 0;
#pragma unroll 1
    for (int s = 0; s < K / 32 - 3; s++) {
        WAIT_VM(8); SBAR(); SCHED0();
        compute(cur);
        WAIT_LGKM0(); SCHED0(); SBAR(); SCHED0();
        stage(cur, s + 3);
        cur = (cur == 2) ? 0 : cur + 1;
    }
    WAIT_VM(8); SBAR(); SCHED0();
    compute(cur); cur = (cur == 2) ? 0 : cur + 1;
    WAIT_VM(4); SBAR(); SCHED0();
    compute(cur); cur = (cur == 2) ? 0 : cur + 1;
    WAIT_VM(0); SBAR(); SCHED0();
    compute(cur);

#pragma unroll
    for (int m = 0; m < 4; m++)
#pragma unroll
        for (int q = 0; q < 4; q++) {
            int row = row0 + wr * 64 + m * 16 + hq * 4 + q;
#pragma unroll
            for (int n = 0; n < 4; n++) {
                int col = col0 + wc * 64 + n * 16 + r15;
                atomicAdd(&hraw[(size_t)row * N + col], acc[m][n][q]);
            }
        }
}

// ---------- expert GEMM: 128x256 tile, 256 thr, 4 waves (64x128 each), 3-stage ----------
// MODE 1: A=xh gathered, B=w1T, K=1024 -> ghid = gate*gelu_fast(acc+b1) (bf16)
// MODE 2: A=ghid, B=w2T, split-K (ks of 2, K-half=2048) -> atomicAdd(out, acc)
template <int MODE>
__global__ __launch_bounds__(256, 2) void k_egemm(
    const ushort_t* __restrict__ A0, const ushort_t* __restrict__ B0,
    const float* __restrict__ bias, const float* __restrict__ gate,
    const int* __restrict__ idx, const int4* __restrict__ tiles,
    const int* __restrict__ meta,
    ushort_t* __restrict__ ghid, float* __restrict__ outA)
{
    constexpr int KF = (MODE == 1) ? DM : DF;      // full K stride of A/B rows
    constexpr int NFULL = (MODE == 1) ? DF : DM;
    constexpr int NS = (MODE == 1) ? (DM / 32) : (2048 / 32);

    int bid = blockIdx.x;
    int xt, yt, kbase = 0;
    if (MODE == 1) {
        // 2112 wgid = 16 xt * 132 y, supertile (8-row y-bands x all xt)
        int wgid = (bid & 7) * 264 + (bid >> 3);   // bijective XCD chunk (2112/8)
        if (wgid < 2048) { int s = wgid >> 7; int r = wgid & 127; xt = r >> 3; yt = s * 8 + (r & 7); }
        else             { int r = wgid - 2048;  xt = r >> 2;     yt = 128 + (r & 3); }
    } else {
        // 1056 = 8 (ks,xt) pairs * 132 y; each XCD owns one pair (B L2-resident)
        int pair = bid & 7;
        yt = bid >> 3;
        kbase = (pair >> 2) * 2048;
        xt = pair & 3;
    }
    if (yt >= meta[0]) return;                     // block-uniform
    int4 ti = tiles[yt];
    int e = ti.x, rstart = ti.y, rows = ti.z, gbase = ti.w;
    int col0 = xt * 256;

    __shared__ ushort_t lA[3][4096];               // 3 x 8KB  (128 rows x 32k)
    __shared__ ushort_t lB[3][8192];               // 3 x 16KB (256 rows x 32k)
    int tid = threadIdx.x, lane = tid & 63, wv = tid >> 6;
    int wr = wv >> 1, wc = wv & 1;                 // wave tile: 64 rows x 128 cols
    int r15 = lane & 15, hq = lane >> 4;

    f32x4 z = {0.f, 0.f, 0.f, 0.f};
    f32x4 acc[4][8];
#pragma unroll
    for (int m = 0; m < 4; m++)
#pragma unroll
        for (int n = 0; n < 8; n++) acc[m][n] = z;

    // staging with 256 threads: each 4KB region holds 64 rows; swz(d)>>6 ALREADY
    // includes the region's row offset (see swz note). BUGFIX vs round 6: do not
    // re-add region row offsets to rB1/rB2/rB3.
    int uA0 = swz(tid * 16);                 // rows 0-63  of lA
    int uA1 = swz(tid * 16 + 4096);          // rows 64-127 of lA
    int uB0 = swz(tid * 16);                 // rows 0-63   of lB
    int uB1 = swz(tid * 16 + 4096);          // rows 64-127
    int uB2 = swz(tid * 16 + 8192);          // rows 128-191
    int uB3 = swz(tid * 16 + 12288);         // rows 192-255
    int rA0 = uA0 >> 6, kA0 = ((uA0 >> 4) & 3) * 8;
    int rA1 = uA1 >> 6, kA1 = ((uA1 >> 4) & 3) * 8;
    int rB0 = uB0 >> 6, kB0 = ((uB0 >> 4) & 3) * 8;
    int rB1 = uB1 >> 6, kB1 = ((uB1 >> 4) & 3) * 8;
    int rB2 = uB2 >> 6, kB2 = ((uB2 >> 4) & 3) * 8;
    int rB3 = uB3 >> 6, kB3 = ((uB3 >> 4) & 3) * 8;

    const ushort_t *Ab0, *Ab1;
    if (MODE == 1) {
        int t0 = idx[e * NTOK + rstart + imin(rA0, rows - 1)];
        int t1 = idx[e * NTOK + rstart + imin(rA1, rows - 1)];
        Ab0 = A0 + (size_t)t0 * KF + kA0;
        Ab1 = A0 + (size_t)t1 * KF + kA1;
    } else {
        Ab0 = A0 + (size_t)(gbase + imin(rA0, rows - 1)) * KF + kbase + kA0;
        Ab1 = A0 + (size_t)(gbase + imin(rA1, rows - 1)) * KF + kbase + kA1;
    }
    const ushort_t* Bb0 = B0 + ((size_t)e * NFULL + col0 + rB0) * KF + kbase + kB0;
    const ushort_t* Bb1 = B0 + ((size_t)e * NFULL + col0 + rB1) * KF + kbase + kB1;
    const ushort_t* Bb2 = B0 + ((size_t)e * NFULL + col0 + rB2) * KF + kbase + kB2;
    const ushort_t* Bb3 = B0 + ((size_t)e * NFULL + col0 + rB3) * KF + kbase + kB3;

    auto stage = [&](int b, int s) {
        int kt = s * 32;
        char* la = (char*)lA + b * 8192;
        char* lb = (char*)lB + b * 16384;
        gload16(Ab0 + kt, la + wv * 1024);
        gload16(Ab1 + kt, la + 4096 + wv * 1024);
        gload16(Bb0 + kt, lb + wv * 1024);
        gload16(Bb1 + kt, lb + 4096 + wv * 1024);
        gload16(Bb2 + kt, lb + 8192 + wv * 1024);
        gload16(Bb3 + kt, lb + 12288 + wv * 1024);
    };
    auto compute = [&](int b) {
        const char* pa = (const char*)lA + b * 8192;
        const char* pb = (const char*)lB + b * 16384;
        bf16x8 af[4], bfr[8];
#pragma unroll
        for (int m = 0; m < 4; m++)
            af[m] = *(const bf16x8*)(pa + swz(((wr * 64 + m * 16 + r15) << 6) + (hq << 4)));
#pragma unroll
        for (int n = 0; n < 8; n++)
            bfr[n] = *(const bf16x8*)(pb + swz(((wc * 128 + n * 16 + r15) << 6) + (hq << 4)));
        __builtin_amdgcn_s_setprio(1);
#pragma unroll
        for (int m = 0; m < 4; m++)
#pragma unroll
            for (int n = 0; n < 8; n++)
                acc[m][n] = __builtin_amdgcn_mfma_f32_16x16x32_bf16(af[m], bfr[n], acc[m][n], 0, 0, 0);
        __builtin_amdgcn_s_setprio(0);
    };

    stage(0, 0); stage(1, 1); stage(2, 2);
    int cur = 0;
#pragma unroll 1
    for (int s = 0; s < NS - 3; s++) {
        WAIT_VM(12); SBAR(); SCHED0();
        compute(cur);
        WAIT_LGKM0(); SCHED0(); SBAR(); SCHED0();
        stage(cur, s + 3);
        cur = (cur == 2) ? 0 : cur + 1;
    }
    WAIT_VM(12); SBAR(); SCHED0();
    compute(cur); cur = (cur == 2) ? 0 : cur + 1;
    WAIT_VM(6); SBAR(); SCHED0();
    compute(cur); cur = (cur == 2) ? 0 : cur + 1;
    WAIT_VM(0); SBAR(); SCHED0();
    compute(cur);

    // epilogue; C layout: col = lane&15, row = (lane>>4)*4 + q  [m89-verified]
    if (MODE == 1) {
#pragma unroll
        for (int m = 0; m < 4; m++)
#pragma unroll
            for (int q = 0; q < 4; q++) {
                int lr = wr * 64 + m * 16 + hq * 4 + q;
                if (lr < rows) {
                    int token = idx[e * NTOK + rstart + lr];
                    float g = gate[token * 4 + e];
                    size_t rb = (size_t)(gbase + lr) * NFULL;
#pragma unroll
                    for (int n = 0; n < 8; n++) {
                        int col = col0 + wc * 128 + n * 16 + r15;
                        float v = gelu_fast(acc[m][n][q] + bias[(size_t)e * NFULL + col]) * g;
                        ghid[rb + col] = f2bf(v);
                    }
                }
            }
    } else {
#pragma unroll
        for (int m = 0; m < 4; m++)
#pragma unroll
            for (int q = 0; q < 4; q++) {
                int lr = wr * 64 + m * 16 + hq * 4 + q;
                if (lr < rows) {
                    int token = idx[e * NTOK + rstart + lr];
#pragma unroll
                    for (int n = 0; n < 8; n++) {
                        int col = col0 + wc * 128 + n * 16 + r15;
                        atomicAdd(&outA[(size_t)token * NFULL + col], acc[m][n][q]);
                    }
                }
            }
    }
}

// ---------- gate: gelu(hraw+br1) dot wr2 (+br2), top-2 softmax, aggregated counts ----------
__global__ __launch_bounds__(256) void k_gate(const float* __restrict__ hraw,
                                              const float* __restrict__ br1,
                                              const float* __restrict__ wr2,
                                              const float* __restrict__ br2,
                                              float* __restrict__ gate,
                                              int* __restrict__ cnt,
                                              int* __restrict__ idxo) {
    __shared__ int smE[128];          // 64 tokens x {i1, i2}
    int tid = threadIdx.x;
    int tl = tid >> 2, q = tid & 3;
    int token = blockIdx.x * 64 + tl;
    const float4* h4 = (const float4*)(hraw + (size_t)token * DH + q * 128);
    const float4* b4 = (const float4*)(br1 + q * 128);
    const float4* w4 = (const float4*)wr2;
    float gx = 0.f, gy = 0.f, gz = 0.f, gw = 0.f;
#pragma unroll
    for (int j = 0; j < 32; j++) {
        float4 hv = h4[j];
        float4 bb = b4[j];
        float h0 = gelu_exact(hv.x + bb.x), h1 = gelu_exact(hv.y + bb.y);
        float h2 = gelu_exact(hv.z + bb.z), h3 = gelu_exact(hv.w + bb.w);
        int k = q * 128 + j * 4;
        float4 w0 = w4[k], w1 = w4[k + 1], w2v = w4[k + 2], w3 = w4[k + 3];
        gx += h0 * w0.x + h1 * w1.x + h2 * w2v.x + h3 * w3.x;
        gy += h0 * w0.y + h1 * w1.y + h2 * w2v.y + h3 * w3.y;
        gz += h0 * w0.z + h1 * w1.z + h2 * w2v.z + h3 * w3.z;
        gw += h0 * w0.w + h1 * w1.w + h2 * w2v.w + h3 * w3.w;
    }
    gx += __shfl_xor(gx, 1); gx += __shfl_xor(gx, 2);
    gy += __shfl_xor(gy, 1); gy += __shfl_xor(gy, 2);
    gz += __shfl_xor(gz, 1); gz += __shfl_xor(gz, 2);
    gw += __shfl_xor(gw, 1); gw += __shfl_xor(gw, 2);
    if (q == 0) {
        float ls[4];
        ls[0] = gx + br2[0]; ls[1] = gy + br2[1]; ls[2] = gz + br2[2]; ls[3] = gw + br2[3];
        int i1 = 0; float m1 = ls[0];
#pragma unroll
        for (int i = 1; i < 4; i++) if (ls[i] > m1) { m1 = ls[i]; i1 = i; }
        int i2 = -1; float m2 = -1e30f;
#pragma unroll
        for (int i = 0; i < 4; i++) if (i != i1 && ls[i] > m2) { m2 = ls[i]; i2 = i; }
        float e0 = (ls[0] >= m2) ? expf(ls[0] - m1) : 0.f;
        float e1 = (ls[1] >= m2) ? expf(ls[1] - m1) : 0.f;
        float e2 = (ls[2] >= m2) ? expf(ls[2] - m1) : 0.f;
        float e3 = (ls[3] >= m2) ? expf(ls[3] - m1) : 0.f;
        float iz = 1.f / (e0 + e1 + e2 + e3);
        float4 g = {e0 * iz, e1 * iz, e2 * iz, e3 * iz};
        ((float4*)gate)[token] = g;
        smE[tl * 2] = i1;
        smE[tl * 2 + 1] = i2;
    }
    __syncthreads();
    if (tid < NE) {
        int e = tid, c = 0;
        for (int s = 0; s < 128; s++) c += (smE[s] == e);
        int base = atomicAdd(&cnt[e], c);
        int r = 0;
        for (int s = 0; s < 128; s++)
            if (smE[s] == e) idxo[e * NTOK + base + (r++)] = blockIdx.x * 64 + (s >> 1);
    }
}

// ---------- tile table over per-expert lists ----------
__global__ void k_tiles(const int* __restrict__ cnt, int4* __restrict__ tiles,
                        int* __restrict__ meta) {
    if (threadIdx.x != 0 || blockIdx.x != 0) return;
    int base = 0, nt = 0;
    for (int e = 0; e < NE; e++) {
        int c = cnt[e];
        for (int r = 0; r < c; r += 128) {
            int4 ti;
            ti.x = e; ti.y = r; ti.z = (c - r < 128) ? (c - r) : 128; ti.w = base + r;
            tiles[nt++] = ti;
        }
        base += c;
    }
    meta[0] = nt;
}

// ---------- out init: out[t][d] = sum_e gate[t][e] * b2[e][d] ----------
__global__ __launch_bounds__(256) void k_init_out(const float* __restrict__ gate,
                                                  const float* __restrict__ b2,
                                                  float* __restrict__ out) {
    int i = blockIdx.x * 256 + threadIdx.x;
    int t = i >> 8;
    int c4 = i & 255;
    float4 g = ((const float4*)gate)[t];
    const float4* b = (const float4*)b2;
    float4 v0 = b[c4], v1 = b[256 + c4], v2 = b[512 + c4], v3 = b[768 + c4];
    float4 o;
    o.x = g.x * v0.x + g.y * v1.x + g.z * v2.x + g.w * v3.x;
    o.y = g.x * v0.y + g.y * v1.y + g.z * v2.y + g.w * v3.y;
    o.z = g.x * v0.z + g.y * v1.z + g.z * v2.z + g.w * v3.z;
    o.w = g.x * v0.w + g.y * v1.w + g.z * v2.w + g.w * v3.w;
    ((float4*)out)[i] = o;
}

extern "C" void kernel_launch(void* const* d_in, const int* in_sizes, int n_in,
                              void* d_out, int out_size, void* d_ws, size_t ws_size,
                              hipStream_t stream) {
    const float* x   = (const float*)d_in[0];
    const float* w1  = (const float*)d_in[1];
    const float* b1  = (const float*)d_in[2];
    const float* w2  = (const float*)d_in[3];
    const float* b2  = (const float*)d_in[4];
    const float* wr1 = (const float*)d_in[5];
    const float* br1 = (const float*)d_in[6];
    const float* wr2 = (const float*)d_in[7];
    const float* br2 = (const float*)d_in[8];
    float* out  = (float*)d_out;
    float* gate = out + (size_t)NTOK * DM;

    char* p = (char*)d_ws;
    auto take = [&](size_t bytes) { char* r = p; p += (bytes + 255) & ~(size_t)255; return r; };
    ushort_t* xh    = (ushort_t*)take((size_t)NTOK * DM * 2);
    ushort_t* w1T   = (ushort_t*)take((size_t)NE * DF * DM * 2);   // [e][N=DF][K=DM]
    ushort_t* w2T   = (ushort_t*)take((size_t)NE * DM * DF * 2);   // [e][N=DM][K=DF]
    ushort_t* wr1Th = (ushort_t*)take((size_t)DH * DM * 2);        // [N=DH][K=DM]
    ushort_t* wr1Tl = (ushort_t*)take((size_t)DH * DM * 2);
    int*      cnt   = (int*)take(64);
    int*      idx   = (int*)take((size_t)NE * NTOK * 4);
    int4*     tiles = (int4*)take(144 * 16);
    int*      meta  = (int*)take(64);
    char*     region = take((size_t)SLOTS * DF * 2);               // ghid overlays xl+h
    ushort_t* xl    = (ushort_t*)region;
    float*    h     = (float*)(region + (size_t)NTOK * DM * 2);
    ushort_t* ghid  = (ushort_t*)region;                           // [slot][DF]

    hipMemsetAsync(cnt, 0, 64, stream);
    hipMemsetAsync(h, 0, (size_t)NTOK * DH * 4, stream);

    // prep
    k_cast_split<<<NTOK * DM / 4 / 256, 256, 0, stream>>>(x, xh, xl, NTOK * DM / 4);
    k_tcast<false><<<dim3(DF / 64, DM / 64, NE), 256, 0, stream>>>(w1, w1T, nullptr, DM, DF);
    k_tcast<false><<<dim3(DM / 64, DF / 64, NE), 256, 0, stream>>>(w2, w2T, nullptr, DF, DM);
    k_tcast<true ><<<dim3(DH / 64, DM / 64, 1),  256, 0, stream>>>(wr1, wr1Th, wr1Tl, DM, DH);

    // router: hraw = x@wr1 via 3 split-terms across grid.z (atomicAdd)
    k_rgemm<<<dim3(DH / 128, NTOK / 128, 3), 256, 0, stream>>>(
        xh, wr1Th, xh, wr1Tl, xl, wr1Th, h);
    k_gate<<<NTOK / 64, 256, 0, stream>>>(h, br1, wr2, br2, gate, cnt, idx);
    k_tiles<<<1, 64, 0, stream>>>(cnt, tiles, meta);
    k_init_out<<<NTOK * DM / 4 / 256, 256, 0, stream>>>(gate, b2, out);

    // sparse expert GEMMs
    k_egemm<1><<<16 * NYT_MAX, 256, 0, stream>>>(
        xh, w1T, b1, gate, idx, tiles, meta, ghid, nullptr);
    k_egemm<2><<<8 * NYT_MAX, 256, 0, stream>>>(
        ghid, w2T, nullptr, gate, idx, tiles, meta, nullptr, out);
}